// Round 8
// baseline (198.960 us; speedup 1.0000x reference)
//
#include <hip/hip_runtime.h>
#include <hip/hip_bf16.h>
#include <math.h>

#define NPOS 147456  // 384*384
#define NSEQ 384

typedef __attribute__((ext_vector_type(4))) float f32x4;
typedef __attribute__((ext_vector_type(8))) short bf16x8;
typedef __attribute__((ext_vector_type(4))) short s16x4;

__device__ __forceinline__ unsigned short f2bf(float f){
  union { float f; unsigned u; } v; v.f = f;
  unsigned r = v.u + 0x7FFFu + ((v.u >> 16) & 1u);
  return (unsigned short)(r >> 16);
}
__device__ __forceinline__ float bf2f(unsigned short h){
  union { unsigned u; float f; } v; v.u = ((unsigned)h) << 16;
  return v.f;
}
__device__ __forceinline__ float fastsig(float x){
  return __builtin_amdgcn_rcpf(1.0f + __expf(-x));
}
// order-explicit packed bf16 pair: lo -> bits[15:0], hi -> bits[31:16]
__device__ __forceinline__ unsigned pk2(float lo, float hi){
  return (unsigned)f2bf(lo) | ((unsigned)f2bf(hi) << 16);
}

// ---------------- all weights fp32 -> bf16, MFMA B-frag order, one launch ----
__global__ void wswz_all(const float* __restrict__ wgi, const float* __restrict__ wpi,
                         const float* __restrict__ wgo, const float* __restrict__ wpo,
                         unsigned short* __restrict__ wgi_s, unsigned short* __restrict__ wpi_s,
                         unsigned short* __restrict__ wgo_s, unsigned short* __restrict__ wpo_s){
  int i = blockIdx.x * 256 + threadIdx.x;   // 48 tiles * 2048
  int t = i >> 11;
  int r = i & 2047;
  const float* src; unsigned short* dst; int lt;
  if (t < 16)      { src = wgi; dst = wgi_s; lt = t;      }
  else if (t < 32) { src = wpi; dst = wpi_s; lt = t - 16; }
  else if (t < 40) { src = wgo; dst = wgo_s; lt = t - 32; }
  else             { src = wpo; dst = wpo_s; lt = t - 40; }
  int j = r & 7, lane = (r >> 3) & 63, kk = (r >> 9) & 3;
  int lrow = lane & 15, khh = lane >> 4;
  dst[lt*2048 + r] = f2bf(src[(lt*16 + lrow)*128 + kk*32 + khh*8 + j]);
}

// ---------------- k1: LN(x) + g_in/p_in/g_out projections ----------------
// TLP-focused restructure: 64 positions/block (grid 2304), 16 KB LDS,
// wave owns 16 rows (1 row-frag). No barriers in the et loop (wave-private
// obuf transpose). Latency hidden by ~6 waves/SIMD instead of ~2.5.
__global__ __launch_bounds__(256, 6) void k1_ln_proj(
    const float* __restrict__ x,
    const float* __restrict__ ln_w, const float* __restrict__ ln_b,
    const unsigned short* __restrict__ wg_sw,
    const unsigned short* __restrict__ wp_sw,
    const unsigned short* __restrict__ wgo_sw,
    unsigned short* __restrict__ a_t,
    unsigned short* __restrict__ b_t,
    unsigned short* __restrict__ g_t)
{
  __shared__ unsigned short xn[64][128];    // 16 KB; per-wave obuf aliases after barrier
  unsigned short* obase = &xn[0][0];

  const int tid  = threadIdx.x;
  const int posb = blockIdx.x * 64;
  const int lane = tid & 63;
  const int wid  = tid >> 6;

  // ---- LN: 4 threads per row (64 rows), stats via shfl ----
  const int row = tid >> 2;
  const int q   = tid & 3;
  {
    const float* xr = x + (size_t)(posb + row) * 128 + q * 32;
    float v[32]; float s = 0.f, s2 = 0.f;
    #pragma unroll
    for (int j2 = 0; j2 < 8; ++j2){
      f32x4 t4 = *(const f32x4*)(xr + j2*4);
      #pragma unroll
      for (int m = 0; m < 4; ++m){ float f = t4[m]; v[j2*4+m] = f; s += f; s2 += f*f; }
    }
    s  += __shfl_xor(s, 1);  s  += __shfl_xor(s, 2);
    s2 += __shfl_xor(s2, 1); s2 += __shfl_xor(s2, 2);
    float mean = s * (1.f/128.f);
    float rstd = rsqrtf(s2 * (1.f/128.f) - mean*mean + 1e-5f);
    int sw = (row & 7) * 8;
    #pragma unroll
    for (int c = 0; c < 4; ++c){
      float n[8];
      #pragma unroll
      for (int j2 = 0; j2 < 8; ++j2){
        int k = q*32 + c*8 + j2;
        n[j2] = (v[c*8+j2] - mean) * rstd * ln_w[k] + ln_b[k];
      }
      uint4 u;
      u.x = pk2(n[0], n[1]); u.y = pk2(n[2], n[3]);
      u.z = pk2(n[4], n[5]); u.w = pk2(n[6], n[7]);
      *(uint4*)&xn[row][(q*32 + c*8) ^ sw] = u;
    }
  }
  __syncthreads();

  // ---- afrag extraction: wave w rows w*16..w*16+15 ----
  const int lrow = lane & 15, kh = lane >> 4;
  bf16x8 afrag[4];
  {
    int r = wid*16 + lrow;
    int sw = (r & 7) * 8;
    #pragma unroll
    for (int kk = 0; kk < 4; ++kk)
      afrag[kk] = *(const bf16x8*)&xn[r][(kk*32 + kh*8) ^ sw];
  }
  __syncthreads();   // all waves done with xn -> per-wave obuf aliasing safe

  // per-wave obuf: [16 ch][24 u16] (row stride 48 B, 16B-aligned); 768 B/wave
  unsigned short* ob = obase + wid * 384;
  const int kh4 = kh * 4;
  const int och = lane >> 2;         // read/store: channel within 16-tile
  const int opo = (lane & 3) * 4;    // read/store: 4 pos per lane
  const size_t posw = (size_t)posb + wid*16;

  // ---- pair loop: sigmoid(g_in) * p_in, 16 col-tiles over e=0..255 ----
  for (int et = 0; et < 16; ++et){
    const unsigned short* wG = wg_sw + (size_t)et*2048 + lane*8;
    const unsigned short* wP = wp_sw + (size_t)et*2048 + lane*8;
    f32x4 accg = {0.f,0.f,0.f,0.f}, accp = {0.f,0.f,0.f,0.f};
    #pragma unroll
    for (int kk = 0; kk < 4; ++kk){
      bf16x8 G = *(const bf16x8*)(wG + kk*512);
      bf16x8 P = *(const bf16x8*)(wP + kk*512);
      accg = __builtin_amdgcn_mfma_f32_16x16x32_bf16(afrag[kk], G, accg, 0, 0, 0);
      accp = __builtin_amdgcn_mfma_f32_16x16x32_bf16(afrag[kk], P, accp, 0, 0, 0);
    }
    {
      uint2 u0;
      u0.x = pk2(fastsig(accg[0])*accp[0], fastsig(accg[1])*accp[1]);
      u0.y = pk2(fastsig(accg[2])*accp[2], fastsig(accg[3])*accp[3]);
      *(uint2*)&ob[lrow*24 + kh4] = u0;
    }
    // same-wave transposed read (in-order DS pipe)
    {
      s16x4 vv = *(const s16x4*)&ob[och*24 + opo];
      int colg = et*16 + och;
      unsigned short* dst = (et < 8) ? (a_t + (size_t)colg * NPOS)
                                     : (b_t + (size_t)(colg - 128) * NPOS);
      *(s16x4*)(dst + posw + opo) = vv;
    }
  }

  // ---- g_out loop: 8 col-tiles over e=0..127 (sigmoid only) ----
  for (int gt = 0; gt < 8; ++gt){
    const unsigned short* wQ = wgo_sw + (size_t)gt*2048 + lane*8;
    f32x4 a0 = {0.f,0.f,0.f,0.f};
    #pragma unroll
    for (int kk = 0; kk < 4; ++kk){
      bf16x8 Q = *(const bf16x8*)(wQ + kk*512);
      a0 = __builtin_amdgcn_mfma_f32_16x16x32_bf16(afrag[kk], Q, a0, 0, 0, 0);
    }
    {
      uint2 u0;
      u0.x = pk2(fastsig(a0[0]), fastsig(a0[1]));
      u0.y = pk2(fastsig(a0[2]), fastsig(a0[3]));
      *(uint2*)&ob[lrow*24 + kh4] = u0;
    }
    {
      s16x4 vv = *(const s16x4*)&ob[och*24 + opo];
      *(s16x4*)(g_t + (size_t)(gt*16 + och) * NPOS + posw + opo) = vv;
    }
  }
}

// ---------------- k2: triangle einsum, batched per channel d ----------------
#define K2PAD 56
__global__ __launch_bounds__(256) void k2_tri(
    const unsigned short* __restrict__ a_t,
    const unsigned short* __restrict__ b_t,
    unsigned short* __restrict__ t_t)
{
  __shared__ unsigned short As[128][K2PAD];
  __shared__ unsigned short Bs[128][K2PAD];

  const int d  = blockIdx.z;
  const int i0 = blockIdx.y * 128;
  const int j0 = blockIdx.x * 128;
  const unsigned short* Ab = a_t + (size_t)d * NPOS;
  const unsigned short* Bb = b_t + (size_t)d * NPOS;

  const int tid = threadIdx.x;
  const int wid = tid >> 6, lane = tid & 63;
  const int wr = wid >> 1, wc = wid & 1;
  const int lrow = lane & 15, kh = (lane >> 4) * 8;

  f32x4 acc[4][4];
  #pragma unroll
  for (int r = 0; r < 4; ++r)
    #pragma unroll
    for (int c = 0; c < 4; ++c)
      acc[r][c] = (f32x4){0.f,0.f,0.f,0.f};

  const int sr = tid >> 1, sc = (tid & 1) * 16;

  for (int k0 = 0; k0 < NSEQ; k0 += 32){
    bf16x8 va0 = *(const bf16x8*)(Ab + (size_t)(i0 + sr) * NSEQ + k0 + sc);
    bf16x8 va1 = *(const bf16x8*)(Ab + (size_t)(i0 + sr) * NSEQ + k0 + sc + 8);
    bf16x8 vb0 = *(const bf16x8*)(Bb + (size_t)(j0 + sr) * NSEQ + k0 + sc);
    bf16x8 vb1 = *(const bf16x8*)(Bb + (size_t)(j0 + sr) * NSEQ + k0 + sc + 8);
    __syncthreads();
    *(bf16x8*)&As[sr][sc]     = va0;
    *(bf16x8*)&As[sr][sc + 8] = va1;
    *(bf16x8*)&Bs[sr][sc]     = vb0;
    *(bf16x8*)&Bs[sr][sc + 8] = vb1;
    __syncthreads();

    bf16x8 af[4], bfr[4];
    #pragma unroll
    for (int r = 0; r < 4; ++r)
      af[r] = *(const bf16x8*)&As[wr*64 + r*16 + lrow][kh];
    #pragma unroll
    for (int c = 0; c < 4; ++c)
      bfr[c] = *(const bf16x8*)&Bs[wc*64 + c*16 + lrow][kh];
    #pragma unroll
    for (int r = 0; r < 4; ++r)
      #pragma unroll
      for (int c = 0; c < 4; ++c)
        acc[r][c] = __builtin_amdgcn_mfma_f32_16x16x32_bf16(af[r], bfr[c], acc[r][c], 0, 0, 0);
  }

  unsigned short* Tb = t_t + (size_t)d * NPOS;
  #pragma unroll
  for (int r = 0; r < 4; ++r){
    int i = i0 + wr*64 + r*16 + (lane >> 4) * 4;
    #pragma unroll
    for (int c = 0; c < 4; ++c){
      int j = j0 + wc*64 + c*16 + lrow;
      #pragma unroll
      for (int jj = 0; jj < 4; ++jj)
        Tb[(size_t)(i + jj) * NSEQ + j] = f2bf(acc[r][c][jj]);
    }
  }
}

// ---------------- k3: LN(t) over d + out-projection + gate ----------------
#define LNS 136
__global__ __launch_bounds__(256, 3) void k3_out(
    const unsigned short* __restrict__ t_t,
    const unsigned short* __restrict__ g_t,
    const float* __restrict__ ln_w, const float* __restrict__ ln_b,
    const unsigned short* __restrict__ wpo_sw,
    float* __restrict__ out)
{
  __shared__ unsigned short traw[128][136];  // t tile, later g tile
  __shared__ float regB[9024];
  __shared__ float smean[128], srs[128];

  const int tid = threadIdx.x;
  const int p0  = blockIdx.x * 128;
  const int lane = tid & 63, wid = tid >> 6;

  float* pps = regB;                              // [16][128]
  float* ppq = regB + 2048;                       // [16][128]
  unsigned short* lnt = (unsigned short*)regB;    // [128][LNS]
  float (*ltile)[68] = (float(*)[68])regB;        // [128][68]

  {
    int d = tid >> 1, c0 = (tid & 1) * 64;
    const unsigned short* src = t_t + (size_t)d * NPOS + p0 + c0;
    #pragma unroll
    for (int j = 0; j < 8; ++j)
      *(bf16x8*)&traw[d][c0 + j*8] = *(const bf16x8*)(src + j*8);
  }
  __syncthreads();

  const int pg = tid & 15, dh = tid >> 4;
  {
    float s8[8] = {0,0,0,0,0,0,0,0}, q8[8] = {0,0,0,0,0,0,0,0};
    #pragma unroll
    for (int jd = 0; jd < 8; ++jd){
      bf16x8 v = *(const bf16x8*)&traw[dh*8 + jd][pg*8];
      #pragma unroll
      for (int p = 0; p < 8; ++p){
        float f = bf2f((unsigned short)v[p]);
        s8[p] += f; q8[p] += f*f;
      }
    }
    #pragma unroll
    for (int p = 0; p < 8; ++p){
      pps[dh*128 + pg*8 + p] = s8[p];
      ppq[dh*128 + pg*8 + p] = q8[p];
    }
  }
  __syncthreads();
  if (tid < 128){
    float s = 0.f, q = 0.f;
    #pragma unroll
    for (int k = 0; k < 16; ++k){ s += pps[k*128 + tid]; q += ppq[k*128 + tid]; }
    float m = s * (1.f/128.f);
    smean[tid] = m;
    srs[tid]   = rsqrtf(q * (1.f/128.f) - m*m + 1e-5f);
  }
  __syncthreads();

  {
    float vv[8][8];
    #pragma unroll
    for (int jd = 0; jd < 8; ++jd){
      bf16x8 v = *(const bf16x8*)&traw[dh*8 + jd][pg*8];
      float w = ln_w[dh*8 + jd], bb = ln_b[dh*8 + jd];
      #pragma unroll
      for (int p = 0; p < 8; ++p)
        vv[jd][p] = (bf2f((unsigned short)v[p]) - smean[pg*8+p]) * srs[pg*8+p] * w + bb;
    }
    #pragma unroll
    for (int p = 0; p < 8; ++p){
      uint4 u;
      u.x = pk2(vv[0][p], vv[1][p]); u.y = pk2(vv[2][p], vv[3][p]);
      u.z = pk2(vv[4][p], vv[5][p]); u.w = pk2(vv[6][p], vv[7][p]);
      *(uint4*)&lnt[(size_t)(pg*8 + p)*LNS + dh*8] = u;
    }
  }
  __syncthreads();

  const int lrow = lane & 15, kh = (lane >> 4) * 8;
  bf16x8 af[2][4];
  #pragma unroll
  for (int r = 0; r < 2; ++r)
    #pragma unroll
    for (int kk = 0; kk < 4; ++kk)
      af[r][kk] = *(const bf16x8*)&lnt[(size_t)(wid*32 + r*16 + lrow)*LNS + kk*32 + kh];
  __syncthreads();

  {
    int e = tid >> 1, c0 = (tid & 1) * 64;
    const unsigned short* src = g_t + (size_t)e * NPOS + p0 + c0;
    #pragma unroll
    for (int j = 0; j < 8; ++j)
      *(bf16x8*)&traw[e][c0 + j*8] = *(const bf16x8*)(src + j*8);
  }
  __syncthreads();

  #pragma unroll
  for (int half = 0; half < 2; ++half){
    #pragma unroll
    for (int cf4 = 0; cf4 < 4; ++cf4){
      int cf = half*4 + cf4;
      const unsigned short* wq = wpo_sw + (size_t)cf*2048 + lane*8;
      bf16x8 bfr[4];
      #pragma unroll
      for (int kk = 0; kk < 4; ++kk)
        bfr[kk] = *(const bf16x8*)(wq + kk*512);
      f32x4 a0 = {0.f,0.f,0.f,0.f}, a1 = {0.f,0.f,0.f,0.f};
      #pragma unroll
      for (int kk = 0; kk < 4; ++kk){
        a0 = __builtin_amdgcn_mfma_f32_16x16x32_bf16(af[0][kk], bfr[kk], a0, 0, 0, 0);
        a1 = __builtin_amdgcn_mfma_f32_16x16x32_bf16(af[1][kk], bfr[kk], a1, 0, 0, 0);
      }
      int e = cf*16 + lrow;
      #pragma unroll
      for (int r = 0; r < 2; ++r){
        f32x4 av = r ? a1 : a0;
        int prow = wid*32 + r*16 + (lane >> 4)*4;
        #pragma unroll
        for (int jj = 0; jj < 4; ++jj){
          float g = bf2f(traw[e][prow + jj]);
          ltile[prow + jj][cf4*16 + lrow] = g * av[jj];
        }
      }
    }
    __syncthreads();
    {
      int pos = tid >> 1, he = tid & 1;
      const float* srcp = &ltile[pos][he*32];
      float* dst = out + (size_t)(p0 + pos)*128 + half*64 + he*32;
      #pragma unroll
      for (int j = 0; j < 8; ++j)
        *(f32x4*)(dst + j*4) = *(const f32x4*)(srcp + j*4);
    }
    __syncthreads();
  }
}

// ---------------- launch ----------------
extern "C" void kernel_launch(void* const* d_in, const int* in_sizes, int n_in,
                              void* d_out, int out_size, void* d_ws, size_t ws_size,
                              hipStream_t stream) {
  (void)in_sizes; (void)n_in; (void)out_size; (void)ws_size;
  const float* x   = (const float*)d_in[0];
  const float* niw = (const float*)d_in[1];
  const float* nib = (const float*)d_in[2];
  const float* wgi = (const float*)d_in[3];
  const float* wpi = (const float*)d_in[4];
  const float* wgo = (const float*)d_in[5];
  const float* now = (const float*)d_in[6];
  const float* nob = (const float*)d_in[7];
  const float* wpo = (const float*)d_in[8];
  float* out = (float*)d_out;

  unsigned short* a_t   = (unsigned short*)d_ws;
  unsigned short* b_t   = a_t + (size_t)128 * NPOS;
  unsigned short* g_t   = b_t + (size_t)128 * NPOS;
  unsigned short* t_t   = g_t + (size_t)128 * NPOS;
  unsigned short* wgi_s = t_t + (size_t)128 * NPOS;
  unsigned short* wpi_s = wgi_s + 256 * 128;
  unsigned short* wgo_s = wpi_s + 256 * 128;
  unsigned short* wpo_s = wgo_s + 128 * 128;

  wswz_all<<<384, 256, 0, stream>>>(wgi, wpi, wgo, wpo, wgi_s, wpi_s, wgo_s, wpo_s);

  k1_ln_proj<<<NPOS/64, 256, 0, stream>>>(x, niw, nib, wgi_s, wpi_s, wgo_s, a_t, b_t, g_t);

  dim3 g2(3, 3, 128);
  k2_tri<<<g2, 256, 0, stream>>>(a_t, b_t, t_t);

  k3_out<<<NPOS/128, 256, 0, stream>>>(t_t, g_t, now, nob, wpo_s, out);
}

// Round 9
// 185.996 us; speedup vs baseline: 1.0697x; 1.0697x over previous
//
#include <hip/hip_runtime.h>
#include <hip/hip_bf16.h>
#include <math.h>

#define NPOS 147456  // 384*384
#define NSEQ 384

typedef __attribute__((ext_vector_type(4))) float f32x4;
typedef __attribute__((ext_vector_type(8))) short bf16x8;
typedef __attribute__((ext_vector_type(4))) short s16x4;

__device__ __forceinline__ unsigned short f2bf(float f){
  union { float f; unsigned u; } v; v.f = f;
  unsigned r = v.u + 0x7FFFu + ((v.u >> 16) & 1u);
  return (unsigned short)(r >> 16);
}
__device__ __forceinline__ float bf2f(unsigned short h){
  union { unsigned u; float f; } v; v.u = ((unsigned)h) << 16;
  return v.f;
}
__device__ __forceinline__ float fastsig(float x){
  return __builtin_amdgcn_rcpf(1.0f + __expf(-x));
}
// order-explicit packed bf16 pair: lo -> bits[15:0], hi -> bits[31:16]
__device__ __forceinline__ unsigned pk2(float lo, float hi){
  return (unsigned)f2bf(lo) | ((unsigned)f2bf(hi) << 16);
}

// ---------------- all weights fp32 -> bf16, MFMA B-frag order, one launch ----
__global__ void wswz_all(const float* __restrict__ wgi, const float* __restrict__ wpi,
                         const float* __restrict__ wgo, const float* __restrict__ wpo,
                         unsigned short* __restrict__ wgi_s, unsigned short* __restrict__ wpi_s,
                         unsigned short* __restrict__ wgo_s, unsigned short* __restrict__ wpo_s){
  int i = blockIdx.x * 256 + threadIdx.x;   // 48 tiles * 2048
  int t = i >> 11;
  int r = i & 2047;
  const float* src; unsigned short* dst; int lt;
  if (t < 16)      { src = wgi; dst = wgi_s; lt = t;      }
  else if (t < 32) { src = wpi; dst = wpi_s; lt = t - 16; }
  else if (t < 40) { src = wgo; dst = wgo_s; lt = t - 32; }
  else             { src = wpo; dst = wpo_s; lt = t - 40; }
  int j = r & 7, lane = (r >> 3) & 63, kk = (r >> 9) & 3;
  int lrow = lane & 15, khh = lane >> 4;
  dst[lt*2048 + r] = f2bf(src[(lt*16 + lrow)*128 + kk*32 + khh*8 + j]);
}

// ---------------- k1: LN(x) + g_in/p_in/g_out projections ----------------
// Weight-reuse restructure: 256 positions/block (grid 576), wave owns 64 rows
// (4 row-frags, afrag[4][4] = 64 VGPR). Per-row weight traffic halves vs the
// 32-row/wave variant — k1 time has tracked weight-reads-per-row across r5-r8.
// No barriers in the et loop (wave-private obuf transpose, r7-verified).
__global__ __launch_bounds__(256) void k1_ln_proj(
    const float* __restrict__ x,
    const float* __restrict__ ln_w, const float* __restrict__ ln_b,
    const unsigned short* __restrict__ wg_sw,
    const unsigned short* __restrict__ wp_sw,
    const unsigned short* __restrict__ wgo_sw,
    unsigned short* __restrict__ a_t,
    unsigned short* __restrict__ b_t,
    unsigned short* __restrict__ g_t)
{
  __shared__ unsigned short xn[256][128];   // 64 KB; dead after afrag extraction
  unsigned short* obase = &xn[0][0];        // per-wave obuf aliases xn

  const int tid  = threadIdx.x;
  const int posb = blockIdx.x * 256;
  const int lane = tid & 63;
  const int wid  = tid >> 6;

  // ---- LN: 4 threads per row, 4 passes of 64 rows, stats via shfl ----
  const int rql = tid >> 2;
  const int q   = tid & 3;
  #pragma unroll
  for (int rr = 0; rr < 4; ++rr){
    int row = rr*64 + rql;
    const float* xr = x + (size_t)(posb + row) * 128 + q * 32;
    float v[32]; float s = 0.f, s2 = 0.f;
    #pragma unroll
    for (int j2 = 0; j2 < 8; ++j2){
      f32x4 t4 = *(const f32x4*)(xr + j2*4);
      #pragma unroll
      for (int m = 0; m < 4; ++m){ float f = t4[m]; v[j2*4+m] = f; s += f; s2 += f*f; }
    }
    s  += __shfl_xor(s, 1);  s  += __shfl_xor(s, 2);
    s2 += __shfl_xor(s2, 1); s2 += __shfl_xor(s2, 2);
    float mean = s * (1.f/128.f);
    float rstd = rsqrtf(s2 * (1.f/128.f) - mean*mean + 1e-5f);
    int sw = (row & 7) * 8;
    #pragma unroll
    for (int c = 0; c < 4; ++c){
      float n[8];
      #pragma unroll
      for (int j2 = 0; j2 < 8; ++j2){
        int k = q*32 + c*8 + j2;
        n[j2] = (v[c*8+j2] - mean) * rstd * ln_w[k] + ln_b[k];
      }
      uint4 u;
      u.x = pk2(n[0], n[1]); u.y = pk2(n[2], n[3]);
      u.z = pk2(n[4], n[5]); u.w = pk2(n[6], n[7]);
      *(uint4*)&xn[row][(q*32 + c*8) ^ sw] = u;
    }
  }
  __syncthreads();

  // ---- afrag extraction: wave w rows w*64 + r*16 + lrow, r=0..3 ----
  const int lrow = lane & 15, kh = lane >> 4;
  bf16x8 afrag[4][4];
  #pragma unroll
  for (int r = 0; r < 4; ++r){
    int rw = wid*64 + r*16 + lrow;
    int sw = (rw & 7) * 8;
    #pragma unroll
    for (int kk = 0; kk < 4; ++kk)
      afrag[r][kk] = *(const bf16x8*)&xn[rw][(kk*32 + kh*8) ^ sw];
  }
  __syncthreads();   // xn dead -> per-wave obuf aliasing safe; no barriers below

  // per-wave obuf: [16 ch][72 u16] (row stride 144 B = 9*16: b128-aligned,
  // bank aliasing <= 2-way on both write and read). 2304 B per wave.
  unsigned short* ob = obase + wid * 1152;
  const int kh4 = kh * 4;
  const int och = lane >> 2;          // read/store: channel within 16-tile
  const int opo = (lane & 3) * 16;    // read/store: 16 pos per lane (32 B)
  const size_t posw = (size_t)posb + wid*64;

  // ---- pair loop: sigmoid(g_in) * p_in, 16 col-tiles over e=0..255 ----
  for (int et = 0; et < 16; ++et){
    const unsigned short* wG = wg_sw + (size_t)et*2048 + lane*8;
    const unsigned short* wP = wp_sw + (size_t)et*2048 + lane*8;
    f32x4 accg[4], accp[4];
    #pragma unroll
    for (int r = 0; r < 4; ++r){ accg[r] = (f32x4){0,0,0,0}; accp[r] = (f32x4){0,0,0,0}; }
    #pragma unroll
    for (int kk = 0; kk < 4; ++kk){
      bf16x8 G = *(const bf16x8*)(wG + kk*512);
      bf16x8 P = *(const bf16x8*)(wP + kk*512);
      #pragma unroll
      for (int r = 0; r < 4; ++r){
        accg[r] = __builtin_amdgcn_mfma_f32_16x16x32_bf16(afrag[r][kk], G, accg[r], 0, 0, 0);
        accp[r] = __builtin_amdgcn_mfma_f32_16x16x32_bf16(afrag[r][kk], P, accp[r], 0, 0, 0);
      }
    }
    #pragma unroll
    for (int r = 0; r < 4; ++r){
      uint2 u;
      u.x = pk2(fastsig(accg[r][0])*accp[r][0], fastsig(accg[r][1])*accp[r][1]);
      u.y = pk2(fastsig(accg[r][2])*accp[r][2], fastsig(accg[r][3])*accp[r][3]);
      *(uint2*)&ob[lrow*72 + r*16 + kh4] = u;
    }
    // same-wave transposed read (in-order DS pipe), 32 B per lane
    {
      bf16x8 v0 = *(const bf16x8*)&ob[och*72 + opo];
      bf16x8 v1 = *(const bf16x8*)&ob[och*72 + opo + 8];
      int colg = et*16 + och;
      unsigned short* dst = (et < 8) ? (a_t + (size_t)colg * NPOS)
                                     : (b_t + (size_t)(colg - 128) * NPOS);
      *(bf16x8*)(dst + posw + opo)     = v0;
      *(bf16x8*)(dst + posw + opo + 8) = v1;
    }
  }

  // ---- g_out loop: 8 col-tiles over e=0..127 (sigmoid only) ----
  for (int gt = 0; gt < 8; ++gt){
    const unsigned short* wQ = wgo_sw + (size_t)gt*2048 + lane*8;
    f32x4 acc[4];
    #pragma unroll
    for (int r = 0; r < 4; ++r) acc[r] = (f32x4){0,0,0,0};
    #pragma unroll
    for (int kk = 0; kk < 4; ++kk){
      bf16x8 Q = *(const bf16x8*)(wQ + kk*512);
      #pragma unroll
      for (int r = 0; r < 4; ++r)
        acc[r] = __builtin_amdgcn_mfma_f32_16x16x32_bf16(afrag[r][kk], Q, acc[r], 0, 0, 0);
    }
    #pragma unroll
    for (int r = 0; r < 4; ++r){
      uint2 u;
      u.x = pk2(fastsig(acc[r][0]), fastsig(acc[r][1]));
      u.y = pk2(fastsig(acc[r][2]), fastsig(acc[r][3]));
      *(uint2*)&ob[lrow*72 + r*16 + kh4] = u;
    }
    {
      bf16x8 v0 = *(const bf16x8*)&ob[och*72 + opo];
      bf16x8 v1 = *(const bf16x8*)&ob[och*72 + opo + 8];
      unsigned short* dst = g_t + (size_t)(gt*16 + och) * NPOS;
      *(bf16x8*)(dst + posw + opo)     = v0;
      *(bf16x8*)(dst + posw + opo + 8) = v1;
    }
  }
}

// ---------------- k2: triangle einsum, batched per channel d ----------------
#define K2PAD 56
__global__ __launch_bounds__(256) void k2_tri(
    const unsigned short* __restrict__ a_t,
    const unsigned short* __restrict__ b_t,
    unsigned short* __restrict__ t_t)
{
  __shared__ unsigned short As[128][K2PAD];
  __shared__ unsigned short Bs[128][K2PAD];

  const int d  = blockIdx.z;
  const int i0 = blockIdx.y * 128;
  const int j0 = blockIdx.x * 128;
  const unsigned short* Ab = a_t + (size_t)d * NPOS;
  const unsigned short* Bb = b_t + (size_t)d * NPOS;

  const int tid = threadIdx.x;
  const int wid = tid >> 6, lane = tid & 63;
  const int wr = wid >> 1, wc = wid & 1;
  const int lrow = lane & 15, kh = (lane >> 4) * 8;

  f32x4 acc[4][4];
  #pragma unroll
  for (int r = 0; r < 4; ++r)
    #pragma unroll
    for (int c = 0; c < 4; ++c)
      acc[r][c] = (f32x4){0.f,0.f,0.f,0.f};

  const int sr = tid >> 1, sc = (tid & 1) * 16;

  for (int k0 = 0; k0 < NSEQ; k0 += 32){
    bf16x8 va0 = *(const bf16x8*)(Ab + (size_t)(i0 + sr) * NSEQ + k0 + sc);
    bf16x8 va1 = *(const bf16x8*)(Ab + (size_t)(i0 + sr) * NSEQ + k0 + sc + 8);
    bf16x8 vb0 = *(const bf16x8*)(Bb + (size_t)(j0 + sr) * NSEQ + k0 + sc);
    bf16x8 vb1 = *(const bf16x8*)(Bb + (size_t)(j0 + sr) * NSEQ + k0 + sc + 8);
    __syncthreads();
    *(bf16x8*)&As[sr][sc]     = va0;
    *(bf16x8*)&As[sr][sc + 8] = va1;
    *(bf16x8*)&Bs[sr][sc]     = vb0;
    *(bf16x8*)&Bs[sr][sc + 8] = vb1;
    __syncthreads();

    bf16x8 af[4], bfr[4];
    #pragma unroll
    for (int r = 0; r < 4; ++r)
      af[r] = *(const bf16x8*)&As[wr*64 + r*16 + lrow][kh];
    #pragma unroll
    for (int c = 0; c < 4; ++c)
      bfr[c] = *(const bf16x8*)&Bs[wc*64 + c*16 + lrow][kh];
    #pragma unroll
    for (int r = 0; r < 4; ++r)
      #pragma unroll
      for (int c = 0; c < 4; ++c)
        acc[r][c] = __builtin_amdgcn_mfma_f32_16x16x32_bf16(af[r], bfr[c], acc[r][c], 0, 0, 0);
  }

  unsigned short* Tb = t_t + (size_t)d * NPOS;
  #pragma unroll
  for (int r = 0; r < 4; ++r){
    int i = i0 + wr*64 + r*16 + (lane >> 4) * 4;
    #pragma unroll
    for (int c = 0; c < 4; ++c){
      int j = j0 + wc*64 + c*16 + lrow;
      #pragma unroll
      for (int jj = 0; jj < 4; ++jj)
        Tb[(size_t)(i + jj) * NSEQ + j] = f2bf(acc[r][c][jj]);
    }
  }
}

// ---------------- k3: LN(t) over d + out-projection + gate ----------------
#define LNS 136
__global__ __launch_bounds__(256, 3) void k3_out(
    const unsigned short* __restrict__ t_t,
    const unsigned short* __restrict__ g_t,
    const float* __restrict__ ln_w, const float* __restrict__ ln_b,
    const unsigned short* __restrict__ wpo_sw,
    float* __restrict__ out)
{
  __shared__ unsigned short traw[128][136];  // t tile, later g tile
  __shared__ float regB[9024];
  __shared__ float smean[128], srs[128];

  const int tid = threadIdx.x;
  const int p0  = blockIdx.x * 128;
  const int lane = tid & 63, wid = tid >> 6;

  float* pps = regB;                              // [16][128]
  float* ppq = regB + 2048;                       // [16][128]
  unsigned short* lnt = (unsigned short*)regB;    // [128][LNS]
  float (*ltile)[68] = (float(*)[68])regB;        // [128][68]

  {
    int d = tid >> 1, c0 = (tid & 1) * 64;
    const unsigned short* src = t_t + (size_t)d * NPOS + p0 + c0;
    #pragma unroll
    for (int j = 0; j < 8; ++j)
      *(bf16x8*)&traw[d][c0 + j*8] = *(const bf16x8*)(src + j*8);
  }
  __syncthreads();

  const int pg = tid & 15, dh = tid >> 4;
  {
    float s8[8] = {0,0,0,0,0,0,0,0}, q8[8] = {0,0,0,0,0,0,0,0};
    #pragma unroll
    for (int jd = 0; jd < 8; ++jd){
      bf16x8 v = *(const bf16x8*)&traw[dh*8 + jd][pg*8];
      #pragma unroll
      for (int p = 0; p < 8; ++p){
        float f = bf2f((unsigned short)v[p]);
        s8[p] += f; q8[p] += f*f;
      }
    }
    #pragma unroll
    for (int p = 0; p < 8; ++p){
      pps[dh*128 + pg*8 + p] = s8[p];
      ppq[dh*128 + pg*8 + p] = q8[p];
    }
  }
  __syncthreads();
  if (tid < 128){
    float s = 0.f, q = 0.f;
    #pragma unroll
    for (int k = 0; k < 16; ++k){ s += pps[k*128 + tid]; q += ppq[k*128 + tid]; }
    float m = s * (1.f/128.f);
    smean[tid] = m;
    srs[tid]   = rsqrtf(q * (1.f/128.f) - m*m + 1e-5f);
  }
  __syncthreads();

  {
    float vv[8][8];
    #pragma unroll
    for (int jd = 0; jd < 8; ++jd){
      bf16x8 v = *(const bf16x8*)&traw[dh*8 + jd][pg*8];
      float w = ln_w[dh*8 + jd], bb = ln_b[dh*8 + jd];
      #pragma unroll
      for (int p = 0; p < 8; ++p)
        vv[jd][p] = (bf2f((unsigned short)v[p]) - smean[pg*8+p]) * srs[pg*8+p] * w + bb;
    }
    #pragma unroll
    for (int p = 0; p < 8; ++p){
      uint4 u;
      u.x = pk2(vv[0][p], vv[1][p]); u.y = pk2(vv[2][p], vv[3][p]);
      u.z = pk2(vv[4][p], vv[5][p]); u.w = pk2(vv[6][p], vv[7][p]);
      *(uint4*)&lnt[(size_t)(pg*8 + p)*LNS + dh*8] = u;
    }
  }
  __syncthreads();

  const int lrow = lane & 15, kh = (lane >> 4) * 8;
  bf16x8 af[2][4];
  #pragma unroll
  for (int r = 0; r < 2; ++r)
    #pragma unroll
    for (int kk = 0; kk < 4; ++kk)
      af[r][kk] = *(const bf16x8*)&lnt[(size_t)(wid*32 + r*16 + lrow)*LNS + kk*32 + kh];
  __syncthreads();

  {
    int e = tid >> 1, c0 = (tid & 1) * 64;
    const unsigned short* src = g_t + (size_t)e * NPOS + p0 + c0;
    #pragma unroll
    for (int j = 0; j < 8; ++j)
      *(bf16x8*)&traw[e][c0 + j*8] = *(const bf16x8*)(src + j*8);
  }
  __syncthreads();

  #pragma unroll
  for (int half = 0; half < 2; ++half){
    #pragma unroll
    for (int cf4 = 0; cf4 < 4; ++cf4){
      int cf = half*4 + cf4;
      const unsigned short* wq = wpo_sw + (size_t)cf*2048 + lane*8;
      bf16x8 bfr[4];
      #pragma unroll
      for (int kk = 0; kk < 4; ++kk)
        bfr[kk] = *(const bf16x8*)(wq + kk*512);
      f32x4 a0 = {0.f,0.f,0.f,0.f}, a1 = {0.f,0.f,0.f,0.f};
      #pragma unroll
      for (int kk = 0; kk < 4; ++kk){
        a0 = __builtin_amdgcn_mfma_f32_16x16x32_bf16(af[0][kk], bfr[kk], a0, 0, 0, 0);
        a1 = __builtin_amdgcn_mfma_f32_16x16x32_bf16(af[1][kk], bfr[kk], a1, 0, 0, 0);
      }
      int e = cf*16 + lrow;
      #pragma unroll
      for (int r = 0; r < 2; ++r){
        f32x4 av = r ? a1 : a0;
        int prow = wid*32 + r*16 + (lane >> 4)*4;
        #pragma unroll
        for (int jj = 0; jj < 4; ++jj){
          float g = bf2f(traw[e][prow + jj]);
          ltile[prow + jj][cf4*16 + lrow] = g * av[jj];
        }
      }
    }
    __syncthreads();
    {
      int pos = tid >> 1, he = tid & 1;
      const float* srcp = &ltile[pos][he*32];
      float* dst = out + (size_t)(p0 + pos)*128 + half*64 + he*32;
      #pragma unroll
      for (int j = 0; j < 8; ++j)
        *(f32x4*)(dst + j*4) = *(const f32x4*)(srcp + j*4);
    }
    __syncthreads();
  }
}

// ---------------- launch ----------------
extern "C" void kernel_launch(void* const* d_in, const int* in_sizes, int n_in,
                              void* d_out, int out_size, void* d_ws, size_t ws_size,
                              hipStream_t stream) {
  (void)in_sizes; (void)n_in; (void)out_size; (void)ws_size;
  const float* x   = (const float*)d_in[0];
  const float* niw = (const float*)d_in[1];
  const float* nib = (const float*)d_in[2];
  const float* wgi = (const float*)d_in[3];
  const float* wpi = (const float*)d_in[4];
  const float* wgo = (const float*)d_in[5];
  const float* now = (const float*)d_in[6];
  const float* nob = (const float*)d_in[7];
  const float* wpo = (const float*)d_in[8];
  float* out = (float*)d_out;

  unsigned short* a_t   = (unsigned short*)d_ws;
  unsigned short* b_t   = a_t + (size_t)128 * NPOS;
  unsigned short* g_t   = b_t + (size_t)128 * NPOS;
  unsigned short* t_t   = g_t + (size_t)128 * NPOS;
  unsigned short* wgi_s = t_t + (size_t)128 * NPOS;
  unsigned short* wpi_s = wgi_s + 256 * 128;
  unsigned short* wgo_s = wpi_s + 256 * 128;
  unsigned short* wpo_s = wgo_s + 128 * 128;

  wswz_all<<<384, 256, 0, stream>>>(wgi, wpi, wgo, wpo, wgi_s, wpi_s, wgo_s, wpo_s);

  k1_ln_proj<<<NPOS/256, 256, 0, stream>>>(x, niw, nib, wgi_s, wpi_s, wgo_s, a_t, b_t, g_t);

  dim3 g2(3, 3, 128);
  k2_tri<<<g2, 256, 0, stream>>>(a_t, b_t, t_t);

  k3_out<<<NPOS/128, 256, 0, stream>>>(t_t, g_t, now, nob, wpo_s, out);
}

// Round 10
// 169.301 us; speedup vs baseline: 1.1752x; 1.0986x over previous
//
#include <hip/hip_runtime.h>
#include <hip/hip_bf16.h>
#include <math.h>

#define NPOS 147456  // 384*384
#define NSEQ 384

typedef __attribute__((ext_vector_type(4))) float f32x4;
typedef __attribute__((ext_vector_type(8))) short bf16x8;
typedef __attribute__((ext_vector_type(4))) short s16x4;

__device__ __forceinline__ unsigned short f2bf(float f){
  union { float f; unsigned u; } v; v.f = f;
  unsigned r = v.u + 0x7FFFu + ((v.u >> 16) & 1u);
  return (unsigned short)(r >> 16);
}
__device__ __forceinline__ float bf2f(unsigned short h){
  union { unsigned u; float f; } v; v.u = ((unsigned)h) << 16;
  return v.f;
}
__device__ __forceinline__ float fastsig(float x){
  return __builtin_amdgcn_rcpf(1.0f + __expf(-x));
}
// order-explicit packed bf16 pair: lo -> bits[15:0], hi -> bits[31:16]
__device__ __forceinline__ unsigned pk2(float lo, float hi){
  return (unsigned)f2bf(lo) | ((unsigned)f2bf(hi) << 16);
}

// ---------------- all weights fp32 -> bf16, MFMA B-frag order, one launch ----
__global__ void wswz_all(const float* __restrict__ wgi, const float* __restrict__ wpi,
                         const float* __restrict__ wgo, const float* __restrict__ wpo,
                         unsigned short* __restrict__ wgi_s, unsigned short* __restrict__ wpi_s,
                         unsigned short* __restrict__ wgo_s, unsigned short* __restrict__ wpo_s){
  int i = blockIdx.x * 256 + threadIdx.x;   // 48 tiles * 2048 = 98304 threads exactly
  int t = i >> 11;
  int r = i & 2047;
  const float* src; unsigned short* dst; int lt;
  if (t < 16)      { src = wgi; dst = wgi_s; lt = t;      }
  else if (t < 32) { src = wpi; dst = wpi_s; lt = t - 16; }
  else if (t < 40) { src = wgo; dst = wgo_s; lt = t - 32; }
  else             { src = wpo; dst = wpo_s; lt = t - 40; }
  int j = r & 7, lane = (r >> 3) & 63, kk = (r >> 9) & 3;
  int lrow = lane & 15, khh = lane >> 4;
  dst[lt*2048 + r] = f2bf(src[(lt*16 + lrow)*128 + kk*32 + khh*8 + j]);
}

// ---------------- k1: LN(x) + g_in/p_in/g_out projections ----------------
// ROUND-5 VERBATIM (best measured 80-88 us): 128 pos/block, M=32/wave,
// register weight prefetch double-buffer, block obuf + per-et barrier.
__global__ __launch_bounds__(256, 3) void k1_ln_proj(
    const float* __restrict__ x,
    const float* __restrict__ ln_w, const float* __restrict__ ln_b,
    const unsigned short* __restrict__ wg_sw,
    const unsigned short* __restrict__ wp_sw,
    const unsigned short* __restrict__ wgo_sw,
    unsigned short* __restrict__ a_t,
    unsigned short* __restrict__ b_t,
    unsigned short* __restrict__ g_t)
{
  __shared__ unsigned short xn[128][128];   // 32 KB; later reused as obuf[2][16][136]
  unsigned short (*obuf)[16][136] = reinterpret_cast<unsigned short(*)[16][136]>(&xn[0][0]);

  const int tid  = threadIdx.x;
  const int posb = blockIdx.x * 128;
  const int lane = tid & 63;
  const int wid  = tid >> 6;

  // ---- LN: 4 threads per row, stats via shfl ----
  const int rql = tid >> 2;
  const int q   = tid & 3;
  #pragma unroll
  for (int rr = 0; rr < 2; ++rr){
    int row = rr*64 + rql;
    const float* xr = x + (size_t)(posb + row) * 128 + q * 32;
    float v[32]; float s = 0.f, s2 = 0.f;
    #pragma unroll
    for (int j2 = 0; j2 < 8; ++j2){
      f32x4 t4 = *(const f32x4*)(xr + j2*4);
      #pragma unroll
      for (int m = 0; m < 4; ++m){ float f = t4[m]; v[j2*4+m] = f; s += f; s2 += f*f; }
    }
    s  += __shfl_xor(s, 1);  s  += __shfl_xor(s, 2);
    s2 += __shfl_xor(s2, 1); s2 += __shfl_xor(s2, 2);
    float mean = s * (1.f/128.f);
    float rstd = rsqrtf(s2 * (1.f/128.f) - mean*mean + 1e-5f);
    int sw = (row & 7) * 8;
    #pragma unroll
    for (int c = 0; c < 4; ++c){
      float n[8];
      #pragma unroll
      for (int j2 = 0; j2 < 8; ++j2){
        int k = q*32 + c*8 + j2;
        n[j2] = (v[c*8+j2] - mean) * rstd * ln_w[k] + ln_b[k];
      }
      uint4 u;
      u.x = pk2(n[0], n[1]); u.y = pk2(n[2], n[3]);
      u.z = pk2(n[4], n[5]); u.w = pk2(n[6], n[7]);
      *(uint4*)&xn[row][(q*32 + c*8) ^ sw] = u;
    }
  }
  __syncthreads();

  // ---- afrag extraction: wave w rows w*32..w*32+31 ----
  const int lrow = lane & 15, kh = lane >> 4;
  bf16x8 afrag[2][4];
  #pragma unroll
  for (int r = 0; r < 2; ++r){
    int row = wid*32 + r*16 + lrow;
    int sw = (row & 7) * 8;
    #pragma unroll
    for (int kk = 0; kk < 4; ++kk)
      afrag[r][kk] = *(const bf16x8*)&xn[row][(kk*32 + kh*8) ^ sw];
  }
  __syncthreads();   // xn dead -> obuf space live

  const int kh4 = kh * 4;
  const int scl = wid*4 + kh;        // coop-store: this lane's channel within tile
  const int spo = lrow * 8;          // coop-store: pos offset

#define LOADW_PAIR(G, P, et) do { \
    const unsigned short* _wg = wg_sw + (size_t)(et)*2048 + lane*8; \
    const unsigned short* _wp = wp_sw + (size_t)(et)*2048 + lane*8; \
    _Pragma("unroll") \
    for (int kk = 0; kk < 4; ++kk){ \
      G[kk] = *(const bf16x8*)(_wg + kk*512); \
      P[kk] = *(const bf16x8*)(_wp + kk*512); \
    } } while(0)

#define COMPUTE_PAIR(G, P, et) do { \
    f32x4 accg0 = {0.f,0.f,0.f,0.f}, accg1 = {0.f,0.f,0.f,0.f}; \
    f32x4 accp0 = {0.f,0.f,0.f,0.f}, accp1 = {0.f,0.f,0.f,0.f}; \
    _Pragma("unroll") \
    for (int kk = 0; kk < 4; ++kk){ \
      accg0 = __builtin_amdgcn_mfma_f32_16x16x32_bf16(afrag[0][kk], G[kk], accg0, 0, 0, 0); \
      accg1 = __builtin_amdgcn_mfma_f32_16x16x32_bf16(afrag[1][kk], G[kk], accg1, 0, 0, 0); \
      accp0 = __builtin_amdgcn_mfma_f32_16x16x32_bf16(afrag[0][kk], P[kk], accp0, 0, 0, 0); \
      accp1 = __builtin_amdgcn_mfma_f32_16x16x32_bf16(afrag[1][kk], P[kk], accp1, 0, 0, 0); \
    } \
    { uint2 u0, u1; \
      u0.x = pk2(fastsig(accg0[0])*accp0[0], fastsig(accg0[1])*accp0[1]); \
      u0.y = pk2(fastsig(accg0[2])*accp0[2], fastsig(accg0[3])*accp0[3]); \
      u1.x = pk2(fastsig(accg1[0])*accp1[0], fastsig(accg1[1])*accp1[1]); \
      u1.y = pk2(fastsig(accg1[2])*accp1[2], fastsig(accg1[3])*accp1[3]); \
      *(uint2*)&obuf[(et)&1][lrow][wid*32 + kh4]      = u0; \
      *(uint2*)&obuf[(et)&1][lrow][wid*32 + 16 + kh4] = u1; } \
    __syncthreads(); \
    { bf16x8 vv = *(const bf16x8*)&obuf[(et)&1][scl][spo]; \
      int colg = (et)*16 + scl; \
      unsigned short* dst = ((et) < 8) ? (a_t + (size_t)colg * NPOS) \
                                       : (b_t + (size_t)(colg - 128) * NPOS); \
      *(bf16x8*)(dst + posb + spo) = vv; } \
  } while(0)

  {
    bf16x8 gA[4], pA[4], gB[4], pB[4];
    LOADW_PAIR(gA, pA, 0);
    #pragma unroll
    for (int e2 = 0; e2 < 8; ++e2){
      LOADW_PAIR(gB, pB, e2*2 + 1);
      COMPUTE_PAIR(gA, pA, e2*2);
      if (e2 < 7) LOADW_PAIR(gA, pA, e2*2 + 2);
      COMPUTE_PAIR(gB, pB, e2*2 + 1);
    }
  }

#define LOADW_G(Q, et) do { \
    const unsigned short* _wq = wgo_sw + (size_t)(et)*2048 + lane*8; \
    _Pragma("unroll") \
    for (int kk = 0; kk < 4; ++kk) Q[kk] = *(const bf16x8*)(_wq + kk*512); \
  } while(0)

#define COMPUTE_G(Q, et) do { \
    f32x4 a0 = {0.f,0.f,0.f,0.f}, a1 = {0.f,0.f,0.f,0.f}; \
    _Pragma("unroll") \
    for (int kk = 0; kk < 4; ++kk){ \
      a0 = __builtin_amdgcn_mfma_f32_16x16x32_bf16(afrag[0][kk], Q[kk], a0, 0, 0, 0); \
      a1 = __builtin_amdgcn_mfma_f32_16x16x32_bf16(afrag[1][kk], Q[kk], a1, 0, 0, 0); \
    } \
    { uint2 u0, u1; \
      u0.x = pk2(fastsig(a0[0]), fastsig(a0[1])); \
      u0.y = pk2(fastsig(a0[2]), fastsig(a0[3])); \
      u1.x = pk2(fastsig(a1[0]), fastsig(a1[1])); \
      u1.y = pk2(fastsig(a1[2]), fastsig(a1[3])); \
      *(uint2*)&obuf[(et)&1][lrow][wid*32 + kh4]      = u0; \
      *(uint2*)&obuf[(et)&1][lrow][wid*32 + 16 + kh4] = u1; } \
    __syncthreads(); \
    { bf16x8 vv = *(const bf16x8*)&obuf[(et)&1][scl][spo]; \
      *(bf16x8*)(g_t + (size_t)((et)*16 + scl) * NPOS + posb + spo) = vv; } \
  } while(0)

  {
    bf16x8 qA[4], qB[4];
    LOADW_G(qA, 0);
    #pragma unroll
    for (int e2 = 0; e2 < 4; ++e2){
      LOADW_G(qB, e2*2 + 1);
      COMPUTE_G(qA, e2*2);
      if (e2 < 3) LOADW_G(qA, e2*2 + 2);
      COMPUTE_G(qB, e2*2 + 1);
    }
  }
#undef LOADW_PAIR
#undef COMPUTE_PAIR
#undef LOADW_G
#undef COMPUTE_G
}

// ---------------- k2: triangle einsum, batched per channel d ----------------
// K-loop unchanged; NEW epilogue: LDS-transposed coalesced stores.
// ct[64][136] u16 (17.4 KB) reuses the dead As/Bs region (28.7 KB).
#define K2PAD 56
__global__ __launch_bounds__(256) void k2_tri(
    const unsigned short* __restrict__ a_t,
    const unsigned short* __restrict__ b_t,
    unsigned short* __restrict__ t_t)
{
  __shared__ unsigned short smem[128 * K2PAD * 2];   // 28672 B
  unsigned short (*As)[K2PAD] = (unsigned short (*)[K2PAD])smem;
  unsigned short (*Bs)[K2PAD] = (unsigned short (*)[K2PAD])(smem + 128 * K2PAD);

  const int d  = blockIdx.z;
  const int i0 = blockIdx.y * 128;
  const int j0 = blockIdx.x * 128;
  const unsigned short* Ab = a_t + (size_t)d * NPOS;
  const unsigned short* Bb = b_t + (size_t)d * NPOS;

  const int tid = threadIdx.x;
  const int wid = tid >> 6, lane = tid & 63;
  const int wr = wid >> 1, wc = wid & 1;
  const int lrow = lane & 15, kh = (lane >> 4) * 8;

  f32x4 acc[4][4];
  #pragma unroll
  for (int r = 0; r < 4; ++r)
    #pragma unroll
    for (int c = 0; c < 4; ++c)
      acc[r][c] = (f32x4){0.f,0.f,0.f,0.f};

  const int sr = tid >> 1, sc = (tid & 1) * 16;

  for (int k0 = 0; k0 < NSEQ; k0 += 32){
    bf16x8 va0 = *(const bf16x8*)(Ab + (size_t)(i0 + sr) * NSEQ + k0 + sc);
    bf16x8 va1 = *(const bf16x8*)(Ab + (size_t)(i0 + sr) * NSEQ + k0 + sc + 8);
    bf16x8 vb0 = *(const bf16x8*)(Bb + (size_t)(j0 + sr) * NSEQ + k0 + sc);
    bf16x8 vb1 = *(const bf16x8*)(Bb + (size_t)(j0 + sr) * NSEQ + k0 + sc + 8);
    __syncthreads();
    *(bf16x8*)&As[sr][sc]     = va0;
    *(bf16x8*)&As[sr][sc + 8] = va1;
    *(bf16x8*)&Bs[sr][sc]     = vb0;
    *(bf16x8*)&Bs[sr][sc + 8] = vb1;
    __syncthreads();

    bf16x8 af[4], bfr[4];
    #pragma unroll
    for (int r = 0; r < 4; ++r)
      af[r] = *(const bf16x8*)&As[wr*64 + r*16 + lrow][kh];
    #pragma unroll
    for (int c = 0; c < 4; ++c)
      bfr[c] = *(const bf16x8*)&Bs[wc*64 + c*16 + lrow][kh];
    #pragma unroll
    for (int r = 0; r < 4; ++r)
      #pragma unroll
      for (int c = 0; c < 4; ++c)
        acc[r][c] = __builtin_amdgcn_mfma_f32_16x16x32_bf16(af[r], bfr[c], acc[r][c], 0, 0, 0);
  }

  // ---- epilogue: transpose via LDS, fully-coalesced 256B-row stores ----
  __syncthreads();   // As/Bs dead
  unsigned short (*ct)[136] = (unsigned short (*)[136])smem;  // 16B-aligned rows
  unsigned short* Tb = t_t + (size_t)d * NPOS;
  const int lh = lane >> 4;   // 0..3

  #pragma unroll
  for (int p = 0; p < 2; ++p){
    if (wr == p){
      #pragma unroll
      for (int r = 0; r < 4; ++r)
        #pragma unroll
        for (int c = 0; c < 4; ++c)
          #pragma unroll
          for (int jj = 0; jj < 4; ++jj)
            ct[r*16 + lh*4 + jj][wc*64 + c*16 + lrow] = f2bf(acc[r][c][jj]);
    }
    __syncthreads();
    #pragma unroll
    for (int j = 0; j < 4; ++j){
      int row = wid*16 + j*4 + lh;
      bf16x8 v = *(const bf16x8*)&ct[row][lrow*8];
      *(bf16x8*)(Tb + (size_t)(i0 + p*64 + row) * NSEQ + j0 + lrow*8) = v;
    }
    __syncthreads();
  }
}

// ---------------- k3: LN(t) over d + out-projection + gate ----------------
#define LNS 136
__global__ __launch_bounds__(256, 3) void k3_out(
    const unsigned short* __restrict__ t_t,
    const unsigned short* __restrict__ g_t,
    const float* __restrict__ ln_w, const float* __restrict__ ln_b,
    const unsigned short* __restrict__ wpo_sw,
    float* __restrict__ out)
{
  __shared__ unsigned short traw[128][136];  // t tile, later g tile
  __shared__ float regB[9024];
  __shared__ float smean[128], srs[128];

  const int tid = threadIdx.x;
  const int p0  = blockIdx.x * 128;
  const int lane = tid & 63, wid = tid >> 6;

  float* pps = regB;                              // [16][128]
  float* ppq = regB + 2048;                       // [16][128]
  unsigned short* lnt = (unsigned short*)regB;    // [128][LNS]
  float (*ltile)[68] = (float(*)[68])regB;        // [128][68]

  {
    int d = tid >> 1, c0 = (tid & 1) * 64;
    const unsigned short* src = t_t + (size_t)d * NPOS + p0 + c0;
    #pragma unroll
    for (int j = 0; j < 8; ++j)
      *(bf16x8*)&traw[d][c0 + j*8] = *(const bf16x8*)(src + j*8);
  }
  __syncthreads();

  const int pg = tid & 15, dh = tid >> 4;
  {
    float s8[8] = {0,0,0,0,0,0,0,0}, q8[8] = {0,0,0,0,0,0,0,0};
    #pragma unroll
    for (int jd = 0; jd < 8; ++jd){
      bf16x8 v = *(const bf16x8*)&traw[dh*8 + jd][pg*8];
      #pragma unroll
      for (int p = 0; p < 8; ++p){
        float f = bf2f((unsigned short)v[p]);
        s8[p] += f; q8[p] += f*f;
      }
    }
    #pragma unroll
    for (int p = 0; p < 8; ++p){
      pps[dh*128 + pg*8 + p] = s8[p];
      ppq[dh*128 + pg*8 + p] = q8[p];
    }
  }
  __syncthreads();
  if (tid < 128){
    float s = 0.f, q = 0.f;
    #pragma unroll
    for (int k = 0; k < 16; ++k){ s += pps[k*128 + tid]; q += ppq[k*128 + tid]; }
    float m = s * (1.f/128.f);
    smean[tid] = m;
    srs[tid]   = rsqrtf(q * (1.f/128.f) - m*m + 1e-5f);
  }
  __syncthreads();

  {
    float vv[8][8];
    #pragma unroll
    for (int jd = 0; jd < 8; ++jd){
      bf16x8 v = *(const bf16x8*)&traw[dh*8 + jd][pg*8];
      float w = ln_w[dh*8 + jd], bb = ln_b[dh*8 + jd];
      #pragma unroll
      for (int p = 0; p < 8; ++p)
        vv[jd][p] = (bf2f((unsigned short)v[p]) - smean[pg*8+p]) * srs[pg*8+p] * w + bb;
    }
    #pragma unroll
    for (int p = 0; p < 8; ++p){
      uint4 u;
      u.x = pk2(vv[0][p], vv[1][p]); u.y = pk2(vv[2][p], vv[3][p]);
      u.z = pk2(vv[4][p], vv[5][p]); u.w = pk2(vv[6][p], vv[7][p]);
      *(uint4*)&lnt[(size_t)(pg*8 + p)*LNS + dh*8] = u;
    }
  }
  __syncthreads();

  const int lrow = lane & 15, kh = (lane >> 4) * 8;
  bf16x8 af[2][4];
  #pragma unroll
  for (int r = 0; r < 2; ++r)
    #pragma unroll
    for (int kk = 0; kk < 4; ++kk)
      af[r][kk] = *(const bf16x8*)&lnt[(size_t)(wid*32 + r*16 + lrow)*LNS + kk*32 + kh];
  __syncthreads();

  {
    int e = tid >> 1, c0 = (tid & 1) * 64;
    const unsigned short* src = g_t + (size_t)e * NPOS + p0 + c0;
    #pragma unroll
    for (int j = 0; j < 8; ++j)
      *(bf16x8*)&traw[e][c0 + j*8] = *(const bf16x8*)(src + j*8);
  }
  __syncthreads();

  #pragma unroll
  for (int half = 0; half < 2; ++half){
    #pragma unroll
    for (int cf4 = 0; cf4 < 4; ++cf4){
      int cf = half*4 + cf4;
      const unsigned short* wq = wpo_sw + (size_t)cf*2048 + lane*8;
      bf16x8 bfr[4];
      #pragma unroll
      for (int kk = 0; kk < 4; ++kk)
        bfr[kk] = *(const bf16x8*)(wq + kk*512);
      f32x4 a0 = {0.f,0.f,0.f,0.f}, a1 = {0.f,0.f,0.f,0.f};
      #pragma unroll
      for (int kk = 0; kk < 4; ++kk){
        a0 = __builtin_amdgcn_mfma_f32_16x16x32_bf16(af[0][kk], bfr[kk], a0, 0, 0, 0);
        a1 = __builtin_amdgcn_mfma_f32_16x16x32_bf16(af[1][kk], bfr[kk], a1, 0, 0, 0);
      }
      int e = cf*16 + lrow;
      #pragma unroll
      for (int r = 0; r < 2; ++r){
        f32x4 av = r ? a1 : a0;
        int prow = wid*32 + r*16 + (lane >> 4)*4;
        #pragma unroll
        for (int jj = 0; jj < 4; ++jj){
          float g = bf2f(traw[e][prow + jj]);
          ltile[prow + jj][cf4*16 + lrow] = g * av[jj];
        }
      }
    }
    __syncthreads();
    {
      int pos = tid >> 1, he = tid & 1;
      const float* srcp = &ltile[pos][he*32];
      float* dst = out + (size_t)(p0 + pos)*128 + half*64 + he*32;
      #pragma unroll
      for (int j = 0; j < 8; ++j)
        *(f32x4*)(dst + j*4) = *(const f32x4*)(srcp + j*4);
    }
    __syncthreads();
  }
}

// ---------------- launch ----------------
extern "C" void kernel_launch(void* const* d_in, const int* in_sizes, int n_in,
                              void* d_out, int out_size, void* d_ws, size_t ws_size,
                              hipStream_t stream) {
  (void)in_sizes; (void)n_in; (void)out_size; (void)ws_size;
  const float* x   = (const float*)d_in[0];
  const float* niw = (const float*)d_in[1];
  const float* nib = (const float*)d_in[2];
  const float* wgi = (const float*)d_in[3];
  const float* wpi = (const float*)d_in[4];
  const float* wgo = (const float*)d_in[5];
  const float* now = (const float*)d_in[6];
  const float* nob = (const float*)d_in[7];
  const float* wpo = (const float*)d_in[8];
  float* out = (float*)d_out;

  unsigned short* a_t   = (unsigned short*)d_ws;
  unsigned short* b_t   = a_t + (size_t)128 * NPOS;
  unsigned short* g_t   = b_t + (size_t)128 * NPOS;
  unsigned short* t_t   = g_t + (size_t)128 * NPOS;
  unsigned short* wgi_s = t_t + (size_t)128 * NPOS;
  unsigned short* wpi_s = wgi_s + 256 * 128;
  unsigned short* wgo_s = wpi_s + 256 * 128;
  unsigned short* wpo_s = wgo_s + 128 * 128;

  wswz_all<<<384, 256, 0, stream>>>(wgi, wpi, wgo, wpo, wgi_s, wpi_s, wgo_s, wpo_s);

  k1_ln_proj<<<NPOS/128, 256, 0, stream>>>(x, niw, nib, wgi_s, wpi_s, wgo_s, a_t, b_t, g_t);

  dim3 g2(3, 3, 128);
  k2_tri<<<g2, 256, 0, stream>>>(a_t, b_t, t_t);

  k3_out<<<NPOS/128, 256, 0, stream>>>(t_t, g_t, now, nob, wpo_s, out);
}

// Round 11
// 154.046 us; speedup vs baseline: 1.2916x; 1.0990x over previous
//
#include <hip/hip_runtime.h>
#include <hip/hip_bf16.h>
#include <math.h>

#define NPOS 147456  // 384*384
#define NSEQ 384

typedef __attribute__((ext_vector_type(4))) float f32x4;
typedef __attribute__((ext_vector_type(8))) short bf16x8;
typedef __attribute__((ext_vector_type(4))) short s16x4;

__device__ __forceinline__ unsigned short f2bf(float f){
  union { float f; unsigned u; } v; v.f = f;
  unsigned r = v.u + 0x7FFFu + ((v.u >> 16) & 1u);
  return (unsigned short)(r >> 16);
}
__device__ __forceinline__ float bf2f(unsigned short h){
  union { unsigned u; float f; } v; v.u = ((unsigned)h) << 16;
  return v.f;
}
__device__ __forceinline__ float fastsig(float x){
  return __builtin_amdgcn_rcpf(1.0f + __expf(-x));
}
// order-explicit packed bf16 pair: lo -> bits[15:0], hi -> bits[31:16]
__device__ __forceinline__ unsigned pk2(float lo, float hi){
  return (unsigned)f2bf(lo) | ((unsigned)f2bf(hi) << 16);
}

// ---------------- all weights fp32 -> bf16, MFMA B-frag order, one launch ----
__global__ void wswz_all(const float* __restrict__ wgi, const float* __restrict__ wpi,
                         const float* __restrict__ wgo, const float* __restrict__ wpo,
                         unsigned short* __restrict__ wgi_s, unsigned short* __restrict__ wpi_s,
                         unsigned short* __restrict__ wgo_s, unsigned short* __restrict__ wpo_s){
  int i = blockIdx.x * 256 + threadIdx.x;   // 48 tiles * 2048 = 98304 threads exactly
  int t = i >> 11;
  int r = i & 2047;
  const float* src; unsigned short* dst; int lt;
  if (t < 16)      { src = wgi; dst = wgi_s; lt = t;      }
  else if (t < 32) { src = wpi; dst = wpi_s; lt = t - 16; }
  else if (t < 40) { src = wgo; dst = wgo_s; lt = t - 32; }
  else             { src = wpo; dst = wpo_s; lt = t - 40; }
  int j = r & 7, lane = (r >> 3) & 63, kk = (r >> 9) & 3;
  int lrow = lane & 15, khh = lane >> 4;
  dst[lt*2048 + r] = f2bf(src[(lt*16 + lrow)*128 + kk*32 + khh*8 + j]);
}

// ---------------- k1: LN(x) + g_in/p_in/g_out projections ----------------
// ROUND-5 VERBATIM (best measured 80-88 us): 128 pos/block, M=32/wave,
// register weight prefetch double-buffer, block obuf + per-et barrier.
__global__ __launch_bounds__(256, 3) void k1_ln_proj(
    const float* __restrict__ x,
    const float* __restrict__ ln_w, const float* __restrict__ ln_b,
    const unsigned short* __restrict__ wg_sw,
    const unsigned short* __restrict__ wp_sw,
    const unsigned short* __restrict__ wgo_sw,
    unsigned short* __restrict__ a_t,
    unsigned short* __restrict__ b_t,
    unsigned short* __restrict__ g_t)
{
  __shared__ unsigned short xn[128][128];   // 32 KB; later reused as obuf[2][16][136]
  unsigned short (*obuf)[16][136] = reinterpret_cast<unsigned short(*)[16][136]>(&xn[0][0]);

  const int tid  = threadIdx.x;
  const int posb = blockIdx.x * 128;
  const int lane = tid & 63;
  const int wid  = tid >> 6;

  // ---- LN: 4 threads per row, stats via shfl ----
  const int rql = tid >> 2;
  const int q   = tid & 3;
  #pragma unroll
  for (int rr = 0; rr < 2; ++rr){
    int row = rr*64 + rql;
    const float* xr = x + (size_t)(posb + row) * 128 + q * 32;
    float v[32]; float s = 0.f, s2 = 0.f;
    #pragma unroll
    for (int j2 = 0; j2 < 8; ++j2){
      f32x4 t4 = *(const f32x4*)(xr + j2*4);
      #pragma unroll
      for (int m = 0; m < 4; ++m){ float f = t4[m]; v[j2*4+m] = f; s += f; s2 += f*f; }
    }
    s  += __shfl_xor(s, 1);  s  += __shfl_xor(s, 2);
    s2 += __shfl_xor(s2, 1); s2 += __shfl_xor(s2, 2);
    float mean = s * (1.f/128.f);
    float rstd = rsqrtf(s2 * (1.f/128.f) - mean*mean + 1e-5f);
    int sw = (row & 7) * 8;
    #pragma unroll
    for (int c = 0; c < 4; ++c){
      float n[8];
      #pragma unroll
      for (int j2 = 0; j2 < 8; ++j2){
        int k = q*32 + c*8 + j2;
        n[j2] = (v[c*8+j2] - mean) * rstd * ln_w[k] + ln_b[k];
      }
      uint4 u;
      u.x = pk2(n[0], n[1]); u.y = pk2(n[2], n[3]);
      u.z = pk2(n[4], n[5]); u.w = pk2(n[6], n[7]);
      *(uint4*)&xn[row][(q*32 + c*8) ^ sw] = u;
    }
  }
  __syncthreads();

  // ---- afrag extraction: wave w rows w*32..w*32+31 ----
  const int lrow = lane & 15, kh = lane >> 4;
  bf16x8 afrag[2][4];
  #pragma unroll
  for (int r = 0; r < 2; ++r){
    int row = wid*32 + r*16 + lrow;
    int sw = (row & 7) * 8;
    #pragma unroll
    for (int kk = 0; kk < 4; ++kk)
      afrag[r][kk] = *(const bf16x8*)&xn[row][(kk*32 + kh*8) ^ sw];
  }
  __syncthreads();   // xn dead -> obuf space live

  const int kh4 = kh * 4;
  const int scl = wid*4 + kh;        // coop-store: this lane's channel within tile
  const int spo = lrow * 8;          // coop-store: pos offset

#define LOADW_PAIR(G, P, et) do { \
    const unsigned short* _wg = wg_sw + (size_t)(et)*2048 + lane*8; \
    const unsigned short* _wp = wp_sw + (size_t)(et)*2048 + lane*8; \
    _Pragma("unroll") \
    for (int kk = 0; kk < 4; ++kk){ \
      G[kk] = *(const bf16x8*)(_wg + kk*512); \
      P[kk] = *(const bf16x8*)(_wp + kk*512); \
    } } while(0)

#define COMPUTE_PAIR(G, P, et) do { \
    f32x4 accg0 = {0.f,0.f,0.f,0.f}, accg1 = {0.f,0.f,0.f,0.f}; \
    f32x4 accp0 = {0.f,0.f,0.f,0.f}, accp1 = {0.f,0.f,0.f,0.f}; \
    _Pragma("unroll") \
    for (int kk = 0; kk < 4; ++kk){ \
      accg0 = __builtin_amdgcn_mfma_f32_16x16x32_bf16(afrag[0][kk], G[kk], accg0, 0, 0, 0); \
      accg1 = __builtin_amdgcn_mfma_f32_16x16x32_bf16(afrag[1][kk], G[kk], accg1, 0, 0, 0); \
      accp0 = __builtin_amdgcn_mfma_f32_16x16x32_bf16(afrag[0][kk], P[kk], accp0, 0, 0, 0); \
      accp1 = __builtin_amdgcn_mfma_f32_16x16x32_bf16(afrag[1][kk], P[kk], accp1, 0, 0, 0); \
    } \
    { uint2 u0, u1; \
      u0.x = pk2(fastsig(accg0[0])*accp0[0], fastsig(accg0[1])*accp0[1]); \
      u0.y = pk2(fastsig(accg0[2])*accp0[2], fastsig(accg0[3])*accp0[3]); \
      u1.x = pk2(fastsig(accg1[0])*accp1[0], fastsig(accg1[1])*accp1[1]); \
      u1.y = pk2(fastsig(accg1[2])*accp1[2], fastsig(accg1[3])*accp1[3]); \
      *(uint2*)&obuf[(et)&1][lrow][wid*32 + kh4]      = u0; \
      *(uint2*)&obuf[(et)&1][lrow][wid*32 + 16 + kh4] = u1; } \
    __syncthreads(); \
    { bf16x8 vv = *(const bf16x8*)&obuf[(et)&1][scl][spo]; \
      int colg = (et)*16 + scl; \
      unsigned short* dst = ((et) < 8) ? (a_t + (size_t)colg * NPOS) \
                                       : (b_t + (size_t)(colg - 128) * NPOS); \
      *(bf16x8*)(dst + posb + spo) = vv; } \
  } while(0)

  {
    bf16x8 gA[4], pA[4], gB[4], pB[4];
    LOADW_PAIR(gA, pA, 0);
    #pragma unroll
    for (int e2 = 0; e2 < 8; ++e2){
      LOADW_PAIR(gB, pB, e2*2 + 1);
      COMPUTE_PAIR(gA, pA, e2*2);
      if (e2 < 7) LOADW_PAIR(gA, pA, e2*2 + 2);
      COMPUTE_PAIR(gB, pB, e2*2 + 1);
    }
  }

#define LOADW_G(Q, et) do { \
    const unsigned short* _wq = wgo_sw + (size_t)(et)*2048 + lane*8; \
    _Pragma("unroll") \
    for (int kk = 0; kk < 4; ++kk) Q[kk] = *(const bf16x8*)(_wq + kk*512); \
  } while(0)

#define COMPUTE_G(Q, et) do { \
    f32x4 a0 = {0.f,0.f,0.f,0.f}, a1 = {0.f,0.f,0.f,0.f}; \
    _Pragma("unroll") \
    for (int kk = 0; kk < 4; ++kk){ \
      a0 = __builtin_amdgcn_mfma_f32_16x16x32_bf16(afrag[0][kk], Q[kk], a0, 0, 0, 0); \
      a1 = __builtin_amdgcn_mfma_f32_16x16x32_bf16(afrag[1][kk], Q[kk], a1, 0, 0, 0); \
    } \
    { uint2 u0, u1; \
      u0.x = pk2(fastsig(a0[0]), fastsig(a0[1])); \
      u0.y = pk2(fastsig(a0[2]), fastsig(a0[3])); \
      u1.x = pk2(fastsig(a1[0]), fastsig(a1[1])); \
      u1.y = pk2(fastsig(a1[2]), fastsig(a1[3])); \
      *(uint2*)&obuf[(et)&1][lrow][wid*32 + kh4]      = u0; \
      *(uint2*)&obuf[(et)&1][lrow][wid*32 + 16 + kh4] = u1; } \
    __syncthreads(); \
    { bf16x8 vv = *(const bf16x8*)&obuf[(et)&1][scl][spo]; \
      *(bf16x8*)(g_t + (size_t)((et)*16 + scl) * NPOS + posb + spo) = vv; } \
  } while(0)

  {
    bf16x8 qA[4], qB[4];
    LOADW_G(qA, 0);
    #pragma unroll
    for (int e2 = 0; e2 < 4; ++e2){
      LOADW_G(qB, e2*2 + 1);
      COMPUTE_G(qA, e2*2);
      if (e2 < 3) LOADW_G(qA, e2*2 + 2);
      COMPUTE_G(qB, e2*2 + 1);
    }
  }
#undef LOADW_PAIR
#undef COMPUTE_PAIR
#undef LOADW_G
#undef COMPUTE_G
}

// ---------------- k2: triangle einsum, batched per channel d ----------------
// NEW: (a) XCD-aware 1D grid — all 9 (i,j) tiles of one d land on one XCD
// (bid%8 = XCD via hw round-robin), so A/B panels become L2 hits.
// (b) K-step 64: 6 staging phases / 12 barriers instead of 12 / 24.
#define K2S 72   // LDS row stride in u16 (144 B = 9*16: aligned, 2-way bank alias)
__global__ __launch_bounds__(256) void k2_tri(
    const unsigned short* __restrict__ a_t,
    const unsigned short* __restrict__ b_t,
    unsigned short* __restrict__ t_t)
{
  __shared__ unsigned short smem[128 * K2S * 2];   // 36864 B
  unsigned short (*As)[K2S] = (unsigned short (*)[K2S])smem;
  unsigned short (*Bs)[K2S] = (unsigned short (*)[K2S])(smem + 128 * K2S);

  // decode: XCD = bid&7; d = (bid&7) + 8*(group/9); tile = group%9
  const int bid  = blockIdx.x;
  const int gg   = bid >> 3;
  const int d    = (bid & 7) + 8 * (gg / 9);
  const int tile = gg % 9;
  const int i0 = (tile / 3) * 128;
  const int j0 = (tile % 3) * 128;
  const unsigned short* Ab = a_t + (size_t)d * NPOS;
  const unsigned short* Bb = b_t + (size_t)d * NPOS;

  const int tid = threadIdx.x;
  const int wid = tid >> 6, lane = tid & 63;
  const int wr = wid >> 1, wc = wid & 1;
  const int lrow = lane & 15, kh = (lane >> 4) * 8;

  f32x4 acc[4][4];
  #pragma unroll
  for (int r = 0; r < 4; ++r)
    #pragma unroll
    for (int c = 0; c < 4; ++c)
      acc[r][c] = (f32x4){0.f,0.f,0.f,0.f};

  const int sr = tid >> 1, sc = (tid & 1) * 32;   // 2 threads/row, 32 k each

  for (int k0 = 0; k0 < NSEQ; k0 += 64){
    bf16x8 va[4], vb[4];
    #pragma unroll
    for (int j = 0; j < 4; ++j){
      va[j] = *(const bf16x8*)(Ab + (size_t)(i0 + sr) * NSEQ + k0 + sc + j*8);
      vb[j] = *(const bf16x8*)(Bb + (size_t)(j0 + sr) * NSEQ + k0 + sc + j*8);
    }
    __syncthreads();
    #pragma unroll
    for (int j = 0; j < 4; ++j){
      *(bf16x8*)&As[sr][sc + j*8] = va[j];
      *(bf16x8*)&Bs[sr][sc + j*8] = vb[j];
    }
    __syncthreads();

    #pragma unroll
    for (int kc = 0; kc < 64; kc += 32){
      bf16x8 af[4], bfr[4];
      #pragma unroll
      for (int r = 0; r < 4; ++r)
        af[r] = *(const bf16x8*)&As[wr*64 + r*16 + lrow][kc + kh];
      #pragma unroll
      for (int c = 0; c < 4; ++c)
        bfr[c] = *(const bf16x8*)&Bs[wc*64 + c*16 + lrow][kc + kh];
      #pragma unroll
      for (int r = 0; r < 4; ++r)
        #pragma unroll
        for (int c = 0; c < 4; ++c)
          acc[r][c] = __builtin_amdgcn_mfma_f32_16x16x32_bf16(af[r], bfr[c], acc[r][c], 0, 0, 0);
    }
  }

  // ---- epilogue: transpose via LDS, fully-coalesced 256B-row stores ----
  __syncthreads();   // As/Bs dead
  unsigned short (*ct)[136] = (unsigned short (*)[136])smem;  // 16B-aligned rows
  unsigned short* Tb = t_t + (size_t)d * NPOS;
  const int lh = lane >> 4;   // 0..3

  #pragma unroll
  for (int p = 0; p < 2; ++p){
    if (wr == p){
      #pragma unroll
      for (int r = 0; r < 4; ++r)
        #pragma unroll
        for (int c = 0; c < 4; ++c)
          #pragma unroll
          for (int jj = 0; jj < 4; ++jj)
            ct[r*16 + lh*4 + jj][wc*64 + c*16 + lrow] = f2bf(acc[r][c][jj]);
    }
    __syncthreads();
    #pragma unroll
    for (int j = 0; j < 4; ++j){
      int row = wid*16 + j*4 + lh;
      bf16x8 v = *(const bf16x8*)&ct[row][lrow*8];
      *(bf16x8*)(Tb + (size_t)(i0 + p*64 + row) * NSEQ + j0 + lrow*8) = v;
    }
    __syncthreads();
  }
}

// ---------------- k3: LN(t) over d + out-projection + gate ----------------
#define LNS 136
__global__ __launch_bounds__(256, 3) void k3_out(
    const unsigned short* __restrict__ t_t,
    const unsigned short* __restrict__ g_t,
    const float* __restrict__ ln_w, const float* __restrict__ ln_b,
    const unsigned short* __restrict__ wpo_sw,
    float* __restrict__ out)
{
  __shared__ unsigned short traw[128][136];  // t tile, later g tile
  __shared__ float regB[9024];
  __shared__ float smean[128], srs[128];

  const int tid = threadIdx.x;
  const int p0  = blockIdx.x * 128;
  const int lane = tid & 63, wid = tid >> 6;

  float* pps = regB;                              // [16][128]
  float* ppq = regB + 2048;                       // [16][128]
  unsigned short* lnt = (unsigned short*)regB;    // [128][LNS]
  float (*ltile)[68] = (float(*)[68])regB;        // [128][68]

  {
    int d = tid >> 1, c0 = (tid & 1) * 64;
    const unsigned short* src = t_t + (size_t)d * NPOS + p0 + c0;
    #pragma unroll
    for (int j = 0; j < 8; ++j)
      *(bf16x8*)&traw[d][c0 + j*8] = *(const bf16x8*)(src + j*8);
  }
  __syncthreads();

  const int pg = tid & 15, dh = tid >> 4;
  {
    float s8[8] = {0,0,0,0,0,0,0,0}, q8[8] = {0,0,0,0,0,0,0,0};
    #pragma unroll
    for (int jd = 0; jd < 8; ++jd){
      bf16x8 v = *(const bf16x8*)&traw[dh*8 + jd][pg*8];
      #pragma unroll
      for (int p = 0; p < 8; ++p){
        float f = bf2f((unsigned short)v[p]);
        s8[p] += f; q8[p] += f*f;
      }
    }
    #pragma unroll
    for (int p = 0; p < 8; ++p){
      pps[dh*128 + pg*8 + p] = s8[p];
      ppq[dh*128 + pg*8 + p] = q8[p];
    }
  }
  __syncthreads();
  if (tid < 128){
    float s = 0.f, q = 0.f;
    #pragma unroll
    for (int k = 0; k < 16; ++k){ s += pps[k*128 + tid]; q += ppq[k*128 + tid]; }
    float m = s * (1.f/128.f);
    smean[tid] = m;
    srs[tid]   = rsqrtf(q * (1.f/128.f) - m*m + 1e-5f);
  }
  __syncthreads();

  {
    float vv[8][8];
    #pragma unroll
    for (int jd = 0; jd < 8; ++jd){
      bf16x8 v = *(const bf16x8*)&traw[dh*8 + jd][pg*8];
      float w = ln_w[dh*8 + jd], bb = ln_b[dh*8 + jd];
      #pragma unroll
      for (int p = 0; p < 8; ++p)
        vv[jd][p] = (bf2f((unsigned short)v[p]) - smean[pg*8+p]) * srs[pg*8+p] * w + bb;
    }
    #pragma unroll
    for (int p = 0; p < 8; ++p){
      uint4 u;
      u.x = pk2(vv[0][p], vv[1][p]); u.y = pk2(vv[2][p], vv[3][p]);
      u.z = pk2(vv[4][p], vv[5][p]); u.w = pk2(vv[6][p], vv[7][p]);
      *(uint4*)&lnt[(size_t)(pg*8 + p)*LNS + dh*8] = u;
    }
  }
  __syncthreads();

  const int lrow = lane & 15, kh = (lane >> 4) * 8;
  bf16x8 af[2][4];
  #pragma unroll
  for (int r = 0; r < 2; ++r)
    #pragma unroll
    for (int kk = 0; kk < 4; ++kk)
      af[r][kk] = *(const bf16x8*)&lnt[(size_t)(wid*32 + r*16 + lrow)*LNS + kk*32 + kh];
  __syncthreads();

  {
    int e = tid >> 1, c0 = (tid & 1) * 64;
    const unsigned short* src = g_t + (size_t)e * NPOS + p0 + c0;
    #pragma unroll
    for (int j = 0; j < 8; ++j)
      *(bf16x8*)&traw[e][c0 + j*8] = *(const bf16x8*)(src + j*8);
  }
  __syncthreads();

  #pragma unroll
  for (int half = 0; half < 2; ++half){
    #pragma unroll
    for (int cf4 = 0; cf4 < 4; ++cf4){
      int cf = half*4 + cf4;
      const unsigned short* wq = wpo_sw + (size_t)cf*2048 + lane*8;
      bf16x8 bfr[4];
      #pragma unroll
      for (int kk = 0; kk < 4; ++kk)
        bfr[kk] = *(const bf16x8*)(wq + kk*512);
      f32x4 a0 = {0.f,0.f,0.f,0.f}, a1 = {0.f,0.f,0.f,0.f};
      #pragma unroll
      for (int kk = 0; kk < 4; ++kk){
        a0 = __builtin_amdgcn_mfma_f32_16x16x32_bf16(af[0][kk], bfr[kk], a0, 0, 0, 0);
        a1 = __builtin_amdgcn_mfma_f32_16x16x32_bf16(af[1][kk], bfr[kk], a1, 0, 0, 0);
      }
      int e = cf*16 + lrow;
      #pragma unroll
      for (int r = 0; r < 2; ++r){
        f32x4 av = r ? a1 : a0;
        int prow = wid*32 + r*16 + (lane >> 4)*4;
        #pragma unroll
        for (int jj = 0; jj < 4; ++jj){
          float g = bf2f(traw[e][prow + jj]);
          ltile[prow + jj][cf4*16 + lrow] = g * av[jj];
        }
      }
    }
    __syncthreads();
    {
      int pos = tid >> 1, he = tid & 1;
      const float* srcp = &ltile[pos][he*32];
      float* dst = out + (size_t)(p0 + pos)*128 + half*64 + he*32;
      #pragma unroll
      for (int j = 0; j < 8; ++j)
        *(f32x4*)(dst + j*4) = *(const f32x4*)(srcp + j*4);
    }
    __syncthreads();
  }
}

// ---------------- launch ----------------
extern "C" void kernel_launch(void* const* d_in, const int* in_sizes, int n_in,
                              void* d_out, int out_size, void* d_ws, size_t ws_size,
                              hipStream_t stream) {
  (void)in_sizes; (void)n_in; (void)out_size; (void)ws_size;
  const float* x   = (const float*)d_in[0];
  const float* niw = (const float*)d_in[1];
  const float* nib = (const float*)d_in[2];
  const float* wgi = (const float*)d_in[3];
  const float* wpi = (const float*)d_in[4];
  const float* wgo = (const float*)d_in[5];
  const float* now = (const float*)d_in[6];
  const float* nob = (const float*)d_in[7];
  const float* wpo = (const float*)d_in[8];
  float* out = (float*)d_out;

  unsigned short* a_t   = (unsigned short*)d_ws;
  unsigned short* b_t   = a_t + (size_t)128 * NPOS;
  unsigned short* g_t   = b_t + (size_t)128 * NPOS;
  unsigned short* t_t   = g_t + (size_t)128 * NPOS;
  unsigned short* wgi_s = t_t + (size_t)128 * NPOS;
  unsigned short* wpi_s = wgi_s + 256 * 128;
  unsigned short* wgo_s = wpi_s + 256 * 128;
  unsigned short* wpo_s = wgo_s + 128 * 128;

  wswz_all<<<384, 256, 0, stream>>>(wgi, wpi, wgo, wpo, wgi_s, wpi_s, wgo_s, wpo_s);

  k1_ln_proj<<<NPOS/128, 256, 0, stream>>>(x, niw, nib, wgi_s, wpi_s, wgo_s, a_t, b_t, g_t);

  k2_tri<<<1152, 256, 0, stream>>>(a_t, b_t, t_t);

  k3_out<<<NPOS/128, 256, 0, stream>>>(t_t, g_t, now, nob, wpo_s, out);
}

// Round 12
// 135.196 us; speedup vs baseline: 1.4716x; 1.1394x over previous
//
#include <hip/hip_runtime.h>
#include <hip/hip_bf16.h>
#include <math.h>

#define NPOS 147456  // 384*384
#define NSEQ 384

typedef __attribute__((ext_vector_type(4))) float f32x4;
typedef __attribute__((ext_vector_type(8))) short bf16x8;
typedef __attribute__((ext_vector_type(4))) short s16x4;

__device__ __forceinline__ unsigned short f2bf(float f){
  union { float f; unsigned u; } v; v.f = f;
  unsigned r = v.u + 0x7FFFu + ((v.u >> 16) & 1u);
  return (unsigned short)(r >> 16);
}
__device__ __forceinline__ float bf2f(unsigned short h){
  union { unsigned u; float f; } v; v.u = ((unsigned)h) << 16;
  return v.f;
}
__device__ __forceinline__ float fastsig(float x){
  return __builtin_amdgcn_rcpf(1.0f + __expf(-x));
}
// order-explicit packed bf16 pair: lo -> bits[15:0], hi -> bits[31:16]
__device__ __forceinline__ unsigned pk2(float lo, float hi){
  return (unsigned)f2bf(lo) | ((unsigned)f2bf(hi) << 16);
}

// ---------------- all weights fp32 -> bf16, MFMA B-frag order, one launch ----
__global__ void wswz_all(const float* __restrict__ wgi, const float* __restrict__ wpi,
                         const float* __restrict__ wgo, const float* __restrict__ wpo,
                         unsigned short* __restrict__ wgi_s, unsigned short* __restrict__ wpi_s,
                         unsigned short* __restrict__ wgo_s, unsigned short* __restrict__ wpo_s){
  int i = blockIdx.x * 256 + threadIdx.x;   // 48 tiles * 2048 = 98304 threads exactly
  int t = i >> 11;
  int r = i & 2047;
  const float* src; unsigned short* dst; int lt;
  if (t < 16)      { src = wgi; dst = wgi_s; lt = t;      }
  else if (t < 32) { src = wpi; dst = wpi_s; lt = t - 16; }
  else if (t < 40) { src = wgo; dst = wgo_s; lt = t - 32; }
  else             { src = wpo; dst = wpo_s; lt = t - 40; }
  int j = r & 7, lane = (r >> 3) & 63, kk = (r >> 9) & 3;
  int lrow = lane & 15, khh = lane >> 4;
  dst[lt*2048 + r] = f2bf(src[(lt*16 + lrow)*128 + kk*32 + khh*8 + j]);
}

// ---------------- k1: LN(x) + g_in/p_in/g_out projections ----------------
// ROUND-5 VERBATIM (best measured 80-88 us): 128 pos/block, M=32/wave,
// register weight prefetch double-buffer, block obuf + per-et barrier.
__global__ __launch_bounds__(256, 3) void k1_ln_proj(
    const float* __restrict__ x,
    const float* __restrict__ ln_w, const float* __restrict__ ln_b,
    const unsigned short* __restrict__ wg_sw,
    const unsigned short* __restrict__ wp_sw,
    const unsigned short* __restrict__ wgo_sw,
    unsigned short* __restrict__ a_t,
    unsigned short* __restrict__ b_t,
    unsigned short* __restrict__ g_t)
{
  __shared__ unsigned short xn[128][128];   // 32 KB; later reused as obuf[2][16][136]
  unsigned short (*obuf)[16][136] = reinterpret_cast<unsigned short(*)[16][136]>(&xn[0][0]);

  const int tid  = threadIdx.x;
  const int posb = blockIdx.x * 128;
  const int lane = tid & 63;
  const int wid  = tid >> 6;

  // ---- LN: 4 threads per row, stats via shfl ----
  const int rql = tid >> 2;
  const int q   = tid & 3;
  #pragma unroll
  for (int rr = 0; rr < 2; ++rr){
    int row = rr*64 + rql;
    const float* xr = x + (size_t)(posb + row) * 128 + q * 32;
    float v[32]; float s = 0.f, s2 = 0.f;
    #pragma unroll
    for (int j2 = 0; j2 < 8; ++j2){
      f32x4 t4 = *(const f32x4*)(xr + j2*4);
      #pragma unroll
      for (int m = 0; m < 4; ++m){ float f = t4[m]; v[j2*4+m] = f; s += f; s2 += f*f; }
    }
    s  += __shfl_xor(s, 1);  s  += __shfl_xor(s, 2);
    s2 += __shfl_xor(s2, 1); s2 += __shfl_xor(s2, 2);
    float mean = s * (1.f/128.f);
    float rstd = rsqrtf(s2 * (1.f/128.f) - mean*mean + 1e-5f);
    int sw = (row & 7) * 8;
    #pragma unroll
    for (int c = 0; c < 4; ++c){
      float n[8];
      #pragma unroll
      for (int j2 = 0; j2 < 8; ++j2){
        int k = q*32 + c*8 + j2;
        n[j2] = (v[c*8+j2] - mean) * rstd * ln_w[k] + ln_b[k];
      }
      uint4 u;
      u.x = pk2(n[0], n[1]); u.y = pk2(n[2], n[3]);
      u.z = pk2(n[4], n[5]); u.w = pk2(n[6], n[7]);
      *(uint4*)&xn[row][(q*32 + c*8) ^ sw] = u;
    }
  }
  __syncthreads();

  // ---- afrag extraction: wave w rows w*32..w*32+31 ----
  const int lrow = lane & 15, kh = lane >> 4;
  bf16x8 afrag[2][4];
  #pragma unroll
  for (int r = 0; r < 2; ++r){
    int row = wid*32 + r*16 + lrow;
    int sw = (row & 7) * 8;
    #pragma unroll
    for (int kk = 0; kk < 4; ++kk)
      afrag[r][kk] = *(const bf16x8*)&xn[row][(kk*32 + kh*8) ^ sw];
  }
  __syncthreads();   // xn dead -> obuf space live

  const int kh4 = kh * 4;
  const int scl = wid*4 + kh;        // coop-store: this lane's channel within tile
  const int spo = lrow * 8;          // coop-store: pos offset

#define LOADW_PAIR(G, P, et) do { \
    const unsigned short* _wg = wg_sw + (size_t)(et)*2048 + lane*8; \
    const unsigned short* _wp = wp_sw + (size_t)(et)*2048 + lane*8; \
    _Pragma("unroll") \
    for (int kk = 0; kk < 4; ++kk){ \
      G[kk] = *(const bf16x8*)(_wg + kk*512); \
      P[kk] = *(const bf16x8*)(_wp + kk*512); \
    } } while(0)

#define COMPUTE_PAIR(G, P, et) do { \
    f32x4 accg0 = {0.f,0.f,0.f,0.f}, accg1 = {0.f,0.f,0.f,0.f}; \
    f32x4 accp0 = {0.f,0.f,0.f,0.f}, accp1 = {0.f,0.f,0.f,0.f}; \
    _Pragma("unroll") \
    for (int kk = 0; kk < 4; ++kk){ \
      accg0 = __builtin_amdgcn_mfma_f32_16x16x32_bf16(afrag[0][kk], G[kk], accg0, 0, 0, 0); \
      accg1 = __builtin_amdgcn_mfma_f32_16x16x32_bf16(afrag[1][kk], G[kk], accg1, 0, 0, 0); \
      accp0 = __builtin_amdgcn_mfma_f32_16x16x32_bf16(afrag[0][kk], P[kk], accp0, 0, 0, 0); \
      accp1 = __builtin_amdgcn_mfma_f32_16x16x32_bf16(afrag[1][kk], P[kk], accp1, 0, 0, 0); \
    } \
    { uint2 u0, u1; \
      u0.x = pk2(fastsig(accg0[0])*accp0[0], fastsig(accg0[1])*accp0[1]); \
      u0.y = pk2(fastsig(accg0[2])*accp0[2], fastsig(accg0[3])*accp0[3]); \
      u1.x = pk2(fastsig(accg1[0])*accp1[0], fastsig(accg1[1])*accp1[1]); \
      u1.y = pk2(fastsig(accg1[2])*accp1[2], fastsig(accg1[3])*accp1[3]); \
      *(uint2*)&obuf[(et)&1][lrow][wid*32 + kh4]      = u0; \
      *(uint2*)&obuf[(et)&1][lrow][wid*32 + 16 + kh4] = u1; } \
    __syncthreads(); \
    { bf16x8 vv = *(const bf16x8*)&obuf[(et)&1][scl][spo]; \
      int colg = (et)*16 + scl; \
      unsigned short* dst = ((et) < 8) ? (a_t + (size_t)colg * NPOS) \
                                       : (b_t + (size_t)(colg - 128) * NPOS); \
      *(bf16x8*)(dst + posb + spo) = vv; } \
  } while(0)

  {
    bf16x8 gA[4], pA[4], gB[4], pB[4];
    LOADW_PAIR(gA, pA, 0);
    #pragma unroll
    for (int e2 = 0; e2 < 8; ++e2){
      LOADW_PAIR(gB, pB, e2*2 + 1);
      COMPUTE_PAIR(gA, pA, e2*2);
      if (e2 < 7) LOADW_PAIR(gA, pA, e2*2 + 2);
      COMPUTE_PAIR(gB, pB, e2*2 + 1);
    }
  }

#define LOADW_G(Q, et) do { \
    const unsigned short* _wq = wgo_sw + (size_t)(et)*2048 + lane*8; \
    _Pragma("unroll") \
    for (int kk = 0; kk < 4; ++kk) Q[kk] = *(const bf16x8*)(_wq + kk*512); \
  } while(0)

#define COMPUTE_G(Q, et) do { \
    f32x4 a0 = {0.f,0.f,0.f,0.f}, a1 = {0.f,0.f,0.f,0.f}; \
    _Pragma("unroll") \
    for (int kk = 0; kk < 4; ++kk){ \
      a0 = __builtin_amdgcn_mfma_f32_16x16x32_bf16(afrag[0][kk], Q[kk], a0, 0, 0, 0); \
      a1 = __builtin_amdgcn_mfma_f32_16x16x32_bf16(afrag[1][kk], Q[kk], a1, 0, 0, 0); \
    } \
    { uint2 u0, u1; \
      u0.x = pk2(fastsig(a0[0]), fastsig(a0[1])); \
      u0.y = pk2(fastsig(a0[2]), fastsig(a0[3])); \
      u1.x = pk2(fastsig(a1[0]), fastsig(a1[1])); \
      u1.y = pk2(fastsig(a1[2]), fastsig(a1[3])); \
      *(uint2*)&obuf[(et)&1][lrow][wid*32 + kh4]      = u0; \
      *(uint2*)&obuf[(et)&1][lrow][wid*32 + 16 + kh4] = u1; } \
    __syncthreads(); \
    { bf16x8 vv = *(const bf16x8*)&obuf[(et)&1][scl][spo]; \
      *(bf16x8*)(g_t + (size_t)((et)*16 + scl) * NPOS + posb + spo) = vv; } \
  } while(0)

  {
    bf16x8 qA[4], qB[4];
    LOADW_G(qA, 0);
    #pragma unroll
    for (int e2 = 0; e2 < 4; ++e2){
      LOADW_G(qB, e2*2 + 1);
      COMPUTE_G(qA, e2*2);
      if (e2 < 3) LOADW_G(qA, e2*2 + 2);
      COMPUTE_G(qB, e2*2 + 1);
    }
  }
#undef LOADW_PAIR
#undef COMPUTE_PAIR
#undef LOADW_G
#undef COMPUTE_G
}

// ---------------- k2: triangle einsum, batched per channel d ----------------
// ROUND-11 VERBATIM: XCD-aware 1D grid + K-step 64 + coalesced epilogue.
#define K2S 72   // LDS row stride in u16 (144 B = 9*16: aligned, 2-way bank alias)
__global__ __launch_bounds__(256) void k2_tri(
    const unsigned short* __restrict__ a_t,
    const unsigned short* __restrict__ b_t,
    unsigned short* __restrict__ t_t)
{
  __shared__ unsigned short smem[128 * K2S * 2];   // 36864 B
  unsigned short (*As)[K2S] = (unsigned short (*)[K2S])smem;
  unsigned short (*Bs)[K2S] = (unsigned short (*)[K2S])(smem + 128 * K2S);

  const int bid  = blockIdx.x;
  const int gg   = bid >> 3;
  const int d    = (bid & 7) + 8 * (gg / 9);
  const int tile = gg % 9;
  const int i0 = (tile / 3) * 128;
  const int j0 = (tile % 3) * 128;
  const unsigned short* Ab = a_t + (size_t)d * NPOS;
  const unsigned short* Bb = b_t + (size_t)d * NPOS;

  const int tid = threadIdx.x;
  const int wid = tid >> 6, lane = tid & 63;
  const int wr = wid >> 1, wc = wid & 1;
  const int lrow = lane & 15, kh = (lane >> 4) * 8;

  f32x4 acc[4][4];
  #pragma unroll
  for (int r = 0; r < 4; ++r)
    #pragma unroll
    for (int c = 0; c < 4; ++c)
      acc[r][c] = (f32x4){0.f,0.f,0.f,0.f};

  const int sr = tid >> 1, sc = (tid & 1) * 32;

  for (int k0 = 0; k0 < NSEQ; k0 += 64){
    bf16x8 va[4], vb[4];
    #pragma unroll
    for (int j = 0; j < 4; ++j){
      va[j] = *(const bf16x8*)(Ab + (size_t)(i0 + sr) * NSEQ + k0 + sc + j*8);
      vb[j] = *(const bf16x8*)(Bb + (size_t)(j0 + sr) * NSEQ + k0 + sc + j*8);
    }
    __syncthreads();
    #pragma unroll
    for (int j = 0; j < 4; ++j){
      *(bf16x8*)&As[sr][sc + j*8] = va[j];
      *(bf16x8*)&Bs[sr][sc + j*8] = vb[j];
    }
    __syncthreads();

    #pragma unroll
    for (int kc = 0; kc < 64; kc += 32){
      bf16x8 af[4], bfr[4];
      #pragma unroll
      for (int r = 0; r < 4; ++r)
        af[r] = *(const bf16x8*)&As[wr*64 + r*16 + lrow][kc + kh];
      #pragma unroll
      for (int c = 0; c < 4; ++c)
        bfr[c] = *(const bf16x8*)&Bs[wc*64 + c*16 + lrow][kc + kh];
      #pragma unroll
      for (int r = 0; r < 4; ++r)
        #pragma unroll
        for (int c = 0; c < 4; ++c)
          acc[r][c] = __builtin_amdgcn_mfma_f32_16x16x32_bf16(af[r], bfr[c], acc[r][c], 0, 0, 0);
    }
  }

  __syncthreads();   // As/Bs dead
  unsigned short (*ct)[136] = (unsigned short (*)[136])smem;
  unsigned short* Tb = t_t + (size_t)d * NPOS;
  const int lh = lane >> 4;

  #pragma unroll
  for (int p = 0; p < 2; ++p){
    if (wr == p){
      #pragma unroll
      for (int r = 0; r < 4; ++r)
        #pragma unroll
        for (int c = 0; c < 4; ++c)
          #pragma unroll
          for (int jj = 0; jj < 4; ++jj)
            ct[r*16 + lh*4 + jj][wc*64 + c*16 + lrow] = f2bf(acc[r][c][jj]);
    }
    __syncthreads();
    #pragma unroll
    for (int j = 0; j < 4; ++j){
      int row = wid*16 + j*4 + lh;
      bf16x8 v = *(const bf16x8*)&ct[row][lrow*8];
      *(bf16x8*)(Tb + (size_t)(i0 + p*64 + row) * NSEQ + j0 + lrow*8) = v;
    }
    __syncthreads();
  }
}

// ---------------- k3: LN(t) over d + out-projection + gate ----------------
// RESTRUCTURED: no lnt (normalize-on-read frag build), no ltile (direct
// stores), traw XOR-swizzled (col' = col ^ (((row>>3)&7)*8)) so column
// reads are bank-conflict-free. LDS 51 KB -> 3 blocks/CU; 5 barriers.
__global__ __launch_bounds__(256, 3) void k3_out(
    const unsigned short* __restrict__ t_t,
    const unsigned short* __restrict__ g_t,
    const float* __restrict__ ln_w, const float* __restrict__ ln_b,
    const unsigned short* __restrict__ wpo_sw,
    float* __restrict__ out)
{
  __shared__ unsigned short traw[128][136];  // 34816 B: t tile, later g tile
  __shared__ float pps[16][128];             // 8192 B
  __shared__ float ppq[16][128];             // 8192 B
  __shared__ float smean[128], srs[128];     // 1024 B

  const int tid = threadIdx.x;
  const int p0  = blockIdx.x * 128;
  const int lane = tid & 63, wid = tid >> 6;

  // ---- stage t tile [d][pos], col-swizzled ----
  {
    int d = tid >> 1, c0 = (tid & 1) * 64;
    int sw = ((d >> 3) & 7) * 8;
    const unsigned short* src = t_t + (size_t)d * NPOS + p0 + c0;
    #pragma unroll
    for (int j = 0; j < 8; ++j)
      *(bf16x8*)&traw[d][(c0 + j*8) ^ sw] = *(const bf16x8*)(src + j*8);
  }
  __syncthreads();

  // ---- stats partials: thread = (pg: 8-pos chunk, dh: 8-d chunk) ----
  const int pg = tid & 15, dh = tid >> 4;
  {
    float s8[8] = {0,0,0,0,0,0,0,0}, q8[8] = {0,0,0,0,0,0,0,0};
    int sw = (dh & 7) * 8;
    #pragma unroll
    for (int jd = 0; jd < 8; ++jd){
      bf16x8 v = *(const bf16x8*)&traw[dh*8 + jd][(pg*8) ^ sw];
      #pragma unroll
      for (int p = 0; p < 8; ++p){
        float f = bf2f((unsigned short)v[p]);
        s8[p] += f; q8[p] += f*f;
      }
    }
    #pragma unroll
    for (int p = 0; p < 8; ++p){
      pps[dh][pg*8 + p] = s8[p];
      ppq[dh][pg*8 + p] = q8[p];
    }
  }
  __syncthreads();
  if (tid < 128){
    float s = 0.f, q = 0.f;
    #pragma unroll
    for (int k = 0; k < 16; ++k){ s += pps[k][tid]; q += ppq[k][tid]; }
    float m = s * (1.f/128.f);
    smean[tid] = m;
    srs[tid]   = rsqrtf(q * (1.f/128.f) - m*m + 1e-5f);
  }
  __syncthreads();

  // ---- A-frags via normalize-on-read (column reads, swizzle-keyed on d>>3) ----
  const int lrow = lane & 15, kh = lane >> 4;   // kh in 0..3
  float m2[2], rs2[2];
  #pragma unroll
  for (int r = 0; r < 2; ++r){
    int pos = wid*32 + r*16 + lrow;
    m2[r] = smean[pos];
    rs2[r] = srs[pos];
  }
  bf16x8 af[2][4];
  #pragma unroll
  for (int kk = 0; kk < 4; ++kk){
    int dbase = kk*32 + kh*8;
    int sw = ((dbase >> 3) & 7) * 8;
    f32x4 w0 = *(const f32x4*)(ln_w + dbase);
    f32x4 w1 = *(const f32x4*)(ln_w + dbase + 4);
    f32x4 b0 = *(const f32x4*)(ln_b + dbase);
    f32x4 b1 = *(const f32x4*)(ln_b + dbase + 4);
    #pragma unroll
    for (int r = 0; r < 2; ++r){
      int col = (wid*32 + r*16 + lrow) ^ sw;
      float n[8];
      #pragma unroll
      for (int j = 0; j < 4; ++j)
        n[j] = (bf2f(traw[dbase + j][col]) - m2[r]) * rs2[r] * w0[j] + b0[j];
      #pragma unroll
      for (int j = 0; j < 4; ++j)
        n[4+j] = (bf2f(traw[dbase + 4 + j][col]) - m2[r]) * rs2[r] * w1[j] + b1[j];
      union { uint4 u; bf16x8 v; } cvt;
      cvt.u.x = pk2(n[0], n[1]); cvt.u.y = pk2(n[2], n[3]);
      cvt.u.z = pk2(n[4], n[5]); cvt.u.w = pk2(n[6], n[7]);
      af[r][kk] = cvt.v;
    }
  }
  __syncthreads();   // all waves done reading traw(t)

  // ---- restage g tile [e][pos], same swizzle ----
  {
    int e = tid >> 1, c0 = (tid & 1) * 64;
    int sw = ((e >> 3) & 7) * 8;
    const unsigned short* src = g_t + (size_t)e * NPOS + p0 + c0;
    #pragma unroll
    for (int j = 0; j < 8; ++j)
      *(bf16x8*)&traw[e][(c0 + j*8) ^ sw] = *(const bf16x8*)(src + j*8);
  }
  __syncthreads();

  // ---- out-projection + gate, direct stores ----
  for (int cf = 0; cf < 8; ++cf){
    const unsigned short* wq = wpo_sw + (size_t)cf*2048 + lane*8;
    bf16x8 bfr[4];
    #pragma unroll
    for (int kk = 0; kk < 4; ++kk)
      bfr[kk] = *(const bf16x8*)(wq + kk*512);
    f32x4 a0 = {0.f,0.f,0.f,0.f}, a1 = {0.f,0.f,0.f,0.f};
    #pragma unroll
    for (int kk = 0; kk < 4; ++kk){
      a0 = __builtin_amdgcn_mfma_f32_16x16x32_bf16(af[0][kk], bfr[kk], a0, 0, 0, 0);
      a1 = __builtin_amdgcn_mfma_f32_16x16x32_bf16(af[1][kk], bfr[kk], a1, 0, 0, 0);
    }
    int e = cf*16 + lrow;
    int esw = ((e >> 3) & 7) * 8;
    #pragma unroll
    for (int r = 0; r < 2; ++r){
      f32x4 av = r ? a1 : a0;
      int prow = wid*32 + r*16 + kh*4;
      float* op = out + (size_t)(p0 + prow) * 128 + e;
      #pragma unroll
      for (int jj = 0; jj < 4; ++jj){
        float g = bf2f(traw[e][(prow + jj) ^ esw]);
        op[(size_t)jj * 128] = g * av[jj];
      }
    }
  }
}

// ---------------- launch ----------------
extern "C" void kernel_launch(void* const* d_in, const int* in_sizes, int n_in,
                              void* d_out, int out_size, void* d_ws, size_t ws_size,
                              hipStream_t stream) {
  (void)in_sizes; (void)n_in; (void)out_size; (void)ws_size;
  const float* x   = (const float*)d_in[0];
  const float* niw = (const float*)d_in[1];
  const float* nib = (const float*)d_in[2];
  const float* wgi = (const float*)d_in[3];
  const float* wpi = (const float*)d_in[4];
  const float* wgo = (const float*)d_in[5];
  const float* now = (const float*)d_in[6];
  const float* nob = (const float*)d_in[7];
  const float* wpo = (const float*)d_in[8];
  float* out = (float*)d_out;

  unsigned short* a_t   = (unsigned short*)d_ws;
  unsigned short* b_t   = a_t + (size_t)128 * NPOS;
  unsigned short* g_t   = b_t + (size_t)128 * NPOS;
  unsigned short* t_t   = g_t + (size_t)128 * NPOS;
  unsigned short* wgi_s = t_t + (size_t)128 * NPOS;
  unsigned short* wpi_s = wgi_s + 256 * 128;
  unsigned short* wgo_s = wpi_s + 256 * 128;
  unsigned short* wpo_s = wgo_s + 128 * 128;

  wswz_all<<<384, 256, 0, stream>>>(wgi, wpi, wgo, wpo, wgi_s, wpi_s, wgo_s, wpo_s);

  k1_ln_proj<<<NPOS/128, 256, 0, stream>>>(x, niw, nib, wgi_s, wpi_s, wgo_s, a_t, b_t, g_t);

  k2_tri<<<1152, 256, 0, stream>>>(a_t, b_t, t_t);

  k3_out<<<NPOS/128, 256, 0, stream>>>(t_t, g_t, now, nob, wpo_s, out);
}